// Round 4
// baseline (547.536 us; speedup 1.0000x reference)
//
#include <hip/hip_runtime.h>
#include <stdint.h>

typedef unsigned short u16;
typedef __attribute__((ext_vector_type(8))) short bf16x8;
typedef __attribute__((ext_vector_type(4))) float f32x4;

#define MFMA16(a, b, c) __builtin_amdgcn_mfma_f32_16x16x32_bf16(a, b, c, 0, 0, 0)

__device__ __forceinline__ u16 f2bf(float x) {
  union { float f; uint32_t u; } v; v.f = x;
  uint32_t r = (v.u + 0x7FFFu + ((v.u >> 16) & 1u)) >> 16;
  return (u16)r;
}
__device__ __forceinline__ float bf2f(u16 h) {
  union { uint32_t u; float f; } v; v.u = ((uint32_t)h) << 16; return v.f;
}
__device__ __forceinline__ void gll16(const void* g, void* s) {
  __builtin_amdgcn_global_load_lds((const __attribute__((address_space(1))) unsigned int*)g,
                                   (__attribute__((address_space(3))) unsigned int*)s, 16, 0, 0);
}

// ---------------- pack kernels ----------------

// grid (6000,1,3), block 256: fp32 -> bf16, 4 elems/thread
__global__ __launch_bounds__(256) void pack_x_kernel(const float* __restrict__ q,
                                                     const float* __restrict__ k,
                                                     const float* __restrict__ v,
                                                     u16* __restrict__ X) {
  const float* src = blockIdx.z == 0 ? q : (blockIdx.z == 1 ? k : v);
  u16* dst = X + (size_t)blockIdx.z * (6016UL * 1024UL);
  size_t idx = (size_t)blockIdx.x * 1024 + (size_t)threadIdx.x * 4;
  float4 f = *(const float4*)(src + idx);
  ushort4 o;
  o.x = f2bf(f.x); o.y = f2bf(f.y); o.z = f2bf(f.z); o.w = f2bf(f.w);
  *(ushort4*)(dst + idx) = o;
}

// 1 block: bias concat + pos_k bf16 (padded 144 rows) + pos_v^T bf16 (64 x 136)
__global__ __launch_bounds__(256) void pack_misc_kernel(const float* __restrict__ bq,
                                                        const float* __restrict__ bk,
                                                        const float* __restrict__ bv,
                                                        const float* __restrict__ posk,
                                                        const float* __restrict__ posv,
                                                        float* __restrict__ biascat,
                                                        u16* __restrict__ poskbf,
                                                        u16* __restrict__ posvT) {
  for (int i = threadIdx.x; i < 1024; i += 256) {
    biascat[i] = bq[i]; biascat[1024 + i] = bk[i]; biascat[2048 + i] = bv[i];
  }
  for (int i = threadIdx.x; i < 144 * 64; i += 256) {
    int r = i >> 6;
    poskbf[i] = (r < 129) ? f2bf(posk[i]) : (u16)0;
  }
  {
    const int d = threadIdx.x & 63, rr = threadIdx.x >> 6;
#pragma unroll
    for (int j = 0; j < 34; ++j) {
      const int r = rr * 34 + j;
      posvT[d * 136 + r] = (r < 129) ? f2bf(posv[(size_t)r * 64 + d]) : (u16)0;
    }
  }
}

// grid (16,16,3): Wt[z][(n*64+d)*1024 + h] = W[z][n][h][d] (bf16)
__global__ __launch_bounds__(256) void pack_wqkv_kernel(const float* __restrict__ Wq,
                                                        const float* __restrict__ Wk,
                                                        const float* __restrict__ Wv,
                                                        u16* __restrict__ Wt) {
  __shared__ float tile[64][65];
  const float* W = blockIdx.z == 0 ? Wq : (blockIdx.z == 1 ? Wk : Wv);
  u16* dst = Wt + (size_t)blockIdx.z * (1024UL * 1024UL);
  const int n = blockIdx.y, h0 = blockIdx.x * 64;
  const int r = threadIdx.x >> 2, c0 = (threadIdx.x & 3) * 16;
  const float* src = W + (size_t)n * 65536 + (size_t)(h0 + r) * 64 + c0;
#pragma unroll
  for (int j = 0; j < 16; j += 4) {
    float4 f = *(const float4*)(src + j);
    tile[r][c0 + j] = f.x; tile[r][c0 + j + 1] = f.y;
    tile[r][c0 + j + 2] = f.z; tile[r][c0 + j + 3] = f.w;
  }
  __syncthreads();
  u16* outp = dst + (size_t)(n * 64 + r) * 1024 + h0 + c0;
#pragma unroll
  for (int j = 0; j < 16; ++j) outp[j] = f2bf(tile[c0 + j][r]);
}

// grid (16,16): Wfct[o*1024 + i] = Wfc[i*1024 + o] (bf16)
__global__ __launch_bounds__(256) void pack_wfc_kernel(const float* __restrict__ Wfc,
                                                       u16* __restrict__ Wfct) {
  __shared__ float tile[64][65];
  const int i0 = blockIdx.x * 64, o0 = blockIdx.y * 64;
  const int r = threadIdx.x >> 2, c0 = (threadIdx.x & 3) * 16;
  const float* src = Wfc + (size_t)(i0 + r) * 1024 + o0 + c0;
#pragma unroll
  for (int j = 0; j < 16; j += 4) {
    float4 f = *(const float4*)(src + j);
    tile[r][c0 + j] = f.x; tile[r][c0 + j + 1] = f.y;
    tile[r][c0 + j + 2] = f.z; tile[r][c0 + j + 3] = f.w;
  }
  __syncthreads();
  u16* outp = Wfct + (size_t)(o0 + r) * 1024 + i0 + c0;
#pragma unroll
  for (int j = 0; j < 16; ++j) outp[j] = f2bf(tile[c0 + j][r]);
}

// grid (24,64): transpose V [bh][1536][64] -> Vt [bh][64][1536]
__global__ __launch_bounds__(256) void vtrans_kernel(const u16* __restrict__ qkv,
                                                     u16* __restrict__ Vt) {
  const size_t ZS = 4UL * 16 * 1536 * 64;
  __shared__ u16 t[64][72];
  const int bh = blockIdx.y, s0 = blockIdx.x * 64;
  const u16* src = qkv + 2 * ZS + (size_t)bh * (1536UL * 64UL) + (size_t)s0 * 64;
  const int r = threadIdx.x >> 2, c0 = (threadIdx.x & 3) * 16;
  *(uint4*)&t[r][c0]     = *(const uint4*)(src + (size_t)r * 64 + c0);
  *(uint4*)&t[r][c0 + 8] = *(const uint4*)(src + (size_t)r * 64 + c0 + 8);
  __syncthreads();
  uint4 a, bvec;
  uint tmp[8];
#pragma unroll
  for (int j = 0; j < 8; ++j)
    tmp[j] = (uint)t[c0 + 2 * j][r] | ((uint)t[c0 + 2 * j + 1][r] << 16);
  a.x = tmp[0]; a.y = tmp[1]; a.z = tmp[2]; a.w = tmp[3];
  bvec.x = tmp[4]; bvec.y = tmp[5]; bvec.z = tmp[6]; bvec.w = tmp[7];
  u16* dst = Vt + (size_t)(bh * 64 + r) * 1536 + s0 + c0;
  *(uint4*)dst = a;
  *(uint4*)(dst + 8) = bvec;
}

// ---------------- GEMM: C[m,n] = sum_k A[m,k]*Bt[n,k] (+bias), m97-style ----------------
__global__ __launch_bounds__(256) void gemm_bt_kernel(
    const u16* __restrict__ Abase, long aStride,
    const u16* __restrict__ Bbase, long bStride,
    const float* __restrict__ biasBase, long biasStride,
    u16* __restrict__ outBF, float* __restrict__ outF, int mode) {
  const int z = blockIdx.z;
  const u16* A = Abase + (size_t)z * aStride;
  const u16* Bt = Bbase + (size_t)z * bStride;
  const float* bias = biasBase + (size_t)z * biasStride;
  __shared__ u16 As[128 * 32];
  __shared__ u16 Bs[128 * 32];
  const int tid = threadIdx.x, w = tid >> 6, lane = tid & 63;
  const int quad = lane >> 4, l16 = lane & 15;
  const int wm = w >> 1, wn = w & 1;
  const int m0 = blockIdx.y * 128, n0 = blockIdx.x * 128;
  const int srow = w * 16 + (lane >> 2);
  const int scol = (lane & 3) * 8;
  const u16* gA0 = A + (size_t)(m0 + srow) * 1024 + scol;
  const u16* gA1 = gA0 + 64UL * 1024;
  const u16* gB0 = Bt + (size_t)(n0 + srow) * 1024 + scol;
  const u16* gB1 = gB0 + 64UL * 1024;
  u16* lA0 = As + (w * 16) * 32;
  u16* lA1 = As + (64 + w * 16) * 32;
  u16* lB0 = Bs + (w * 16) * 32;
  u16* lB1 = Bs + (64 + w * 16) * 32;

  f32x4 acc[4][4];
  const f32x4 zf = {0.f, 0.f, 0.f, 0.f};
#pragma unroll
  for (int a = 0; a < 4; ++a)
#pragma unroll
    for (int b = 0; b < 4; ++b) acc[a][b] = zf;

  for (int kt = 0; kt < 32; ++kt) {
    const int k0 = kt * 32;
    gll16(gA0 + k0, lA0);
    gll16(gA1 + k0, lA1);
    gll16(gB0 + k0, lB0);
    gll16(gB1 + k0, lB1);
    __syncthreads();
    bf16x8 af[4], bfr[4];
#pragma unroll
    for (int f = 0; f < 4; ++f) {
      af[f]  = *(const bf16x8*)(As + (wm * 64 + f * 16 + l16) * 32 + quad * 8);
      bfr[f] = *(const bf16x8*)(Bs + (wn * 64 + f * 16 + l16) * 32 + quad * 8);
    }
#pragma unroll
    for (int fm = 0; fm < 4; ++fm)
#pragma unroll
      for (int fn = 0; fn < 4; ++fn)
        acc[fm][fn] = MFMA16(af[fm], bfr[fn], acc[fm][fn]);
    __syncthreads();
  }

  if (mode == 0) {
    const float scale = (z == 0) ? 0.125f : 1.0f;
    u16* out = outBF + (size_t)z * (4UL * 16 * 1536 * 64);
#pragma unroll
    for (int fm = 0; fm < 4; ++fm) {
#pragma unroll
      for (int i = 0; i < 4; ++i) {
        const int m = m0 + wm * 64 + fm * 16 + quad * 4 + i;
        if (m >= 6000) continue;
        const int bb = m / 1500;
        const int s = m - bb * 1500;
#pragma unroll
        for (int fn = 0; fn < 4; ++fn) {
          const int n = n0 + wn * 64 + fn * 16 + l16;
          const float vv = (acc[fm][fn][i] + bias[n]) * scale;
          const int h = n >> 6, d = n & 63;
          out[((size_t)(bb * 16 + h) * 1536 + s) * 64 + d] = f2bf(vv);
        }
      }
    }
  } else {
#pragma unroll
    for (int fm = 0; fm < 4; ++fm) {
#pragma unroll
      for (int i = 0; i < 4; ++i) {
        const int m = m0 + wm * 64 + fm * 16 + quad * 4 + i;
        if (m >= 6000) continue;
#pragma unroll
        for (int fn = 0; fn < 4; ++fn) {
          const int n = n0 + wn * 64 + fn * 16 + l16;
          outF[(size_t)m * 1024 + n] = acc[fm][fn][i] + bias[n];
        }
      }
    }
  }
}

// ---------------- fused attention v3: software-pipelined k-loop ----------------
// grid (24, 16, 4), block 256 = 4 independent waves; wave w owns q rows [q0+w*16, +16)
// S^T = K.Q^T MFMA layout: lane holds (k = kc+cg*16+quad*4+i, q = qw0+l16)
struct KF { bf16x8 a0, a1, b0, b1; };
struct VF { bf16x8 v0, v1, v2, v3; };

__global__ __launch_bounds__(256, 4) void attn_kernel(const u16* __restrict__ qkv,
                                                      const u16* __restrict__ Vt,
                                                      const u16* __restrict__ poskbf,
                                                      const u16* __restrict__ posvT,
                                                      const float* __restrict__ posv,
                                                      u16* __restrict__ hidden) {
  const size_t ZS = 4UL * 16 * 1536 * 64;
  __shared__ u16 qp_s[64 * 136];   // bf16 qp[q_local][r], per-wave 16-row slabs
  __shared__ u16 pb_s[64 * 136];   // bf16 in-band rel-v histogram [q_local][delta]
  __shared__ u16 p_s[4 * 16 * 40]; // per-wave P^ tile [q][k], pitch 40

  const int tid = threadIdx.x;
  const int w = tid >> 6, lane = tid & 63, quad = lane >> 4, l16 = lane & 15;
  const int q0 = blockIdx.x * 64, qw0 = q0 + w * 16;
  const int head = blockIdx.y, b = blockIdx.z;
  const int bh = b * 16 + head;
  const size_t sb = (size_t)bh * (1536UL * 64UL);
  const u16* Qp = qkv + sb;
  const u16* Kp = qkv + ZS + sb;
  const u16* Vrow = Vt + (size_t)bh * (64UL * 1536UL) + (size_t)l16 * 1536;
  u16* ps_w = p_s + w * 640;
  u16* qp_row = qp_s + (w * 16 + l16) * 136;
  u16* pb_row = pb_s + (w * 16 + l16) * 136;

  // zero own pb slab (wave-private)
  {
    uint* pz = (uint*)(pb_s + w * 16 * 136);
    for (int i = lane; i < 1088; i += 64) pz[i] = 0u;
  }

  // Q fragment (rows q = qw0 + l16)
  const u16* qptr = Qp + (size_t)(qw0 + l16) * 64 + quad * 8;
  const bf16x8 qB0 = *(const bf16x8*)qptr;
  const bf16x8 qB1 = *(const bf16x8*)(qptr + 32);

  // qp[q][r] = q . pos_k[r] via MFMA; C layout: row q_loc = quad*4+i, col r = l16
#pragma unroll
  for (int nf = 0; nf < 9; ++nf) {
    const u16* bp = poskbf + (size_t)(nf * 16 + l16) * 64 + quad * 8;
    bf16x8 b0 = *(const bf16x8*)bp;
    bf16x8 b1 = *(const bf16x8*)(bp + 32);
    f32x4 c = {0.f, 0.f, 0.f, 0.f};
    c = MFMA16(qB0, b0, c);
    c = MFMA16(qB1, b1, c);
    const int col = nf * 16 + l16;
    if (col < 136) {
#pragma unroll
      for (int i = 0; i < 4; ++i)
        qp_s[(w * 16 + quad * 4 + i) * 136 + col] = f2bf(c[i]);
    }
  }
  __syncthreads();

  const float L2E = 1.44269504f;
  const float M8 = -8.0f * L2E;
  const float eLow  = __builtin_fmaf(bf2f(qp_row[0]), L2E, M8);
  const float eHigh = __builtin_fmaf(bf2f(qp_row[128]), L2E, M8);

  f32x4 accf[4];
  const f32x4 zf = {0.f, 0.f, 0.f, 0.f};
#pragma unroll
  for (int dc = 0; dc < 4; ++dc) accf[dc] = zf;
  // low+high share one accumulator; snapshot at the low->diag boundary
  float sSimple = 0.f, sLowSave = 0.f, sDall = 0.f, sD0 = 0.f, sD128 = 0.f;

  const int itLowEnd = (qw0 >= 95) ? (((qw0 - 95) >> 5) + 1) : 0;
  const int itHigh0 = (qw0 + 110) >> 5;
  const int dEnd = itHigh0 < 46 ? itHigh0 : 46;

  // K fragment loader (by value -> SROA keeps it in VGPRs)
  auto loadK = [&](int it) {
    KF r;
    const u16* kptr = Kp + (size_t)(it * 32 + l16) * 64 + quad * 8;
    r.a0 = *(const bf16x8*)kptr;
    r.a1 = *(const bf16x8*)(kptr + 32);
    r.b0 = *(const bf16x8*)(kptr + 1024);
    r.b1 = *(const bf16x8*)(kptr + 1056);
    return r;
  };
  auto loadV = [&](int it) {
    VF r;
    const u16* vp = Vrow + it * 32 + quad * 8;
    r.v0 = *(const bf16x8*)vp;
    r.v1 = *(const bf16x8*)(vp + 16 * 1536);
    r.v2 = *(const bf16x8*)(vp + 32 * 1536);
    r.v3 = *(const bf16x8*)(vp + 48 * 1536);
    return r;
  };

  KF kcur = loadK(0);
  KF knext;

  for (int it = 0; it < 47; ++it) {
    // in-iteration V prefetch (used at loop bottom) + cross-iteration K prefetch
    VF vcur = loadV(it);
    if (it < 46) knext = loadK(it + 1);
    if (it == itLowEnd) sLowSave = sSimple;

    const int phase = (it < itLowEnd) ? 0 : ((it >= 46) ? 1 : ((it < dEnd) ? 1 : 2));

    // diag bias LDS reads issued before MFMAs (index-only dependence)
    float qb[2][4];
    if (phase == 1) {
      const int base = it * 32 + 64 - qw0 - l16;
#pragma unroll
      for (int cg = 0; cg < 2; ++cg) {
#pragma unroll
        for (int i = 0; i < 4; ++i) {
          int delta = base + cg * 16 + quad * 4 + i;
          delta = delta < 0 ? 0 : (delta > 128 ? 128 : delta);
          qb[cg][i] = bf2f(qp_row[delta]);
        }
      }
    }

    f32x4 cc[2];
    cc[0] = zf; cc[1] = zf;
    cc[0] = MFMA16(kcur.a0, qB0, cc[0]);
    cc[0] = MFMA16(kcur.a1, qB1, cc[0]);
    cc[1] = MFMA16(kcur.b0, qB0, cc[1]);
    cc[1] = MFMA16(kcur.b1, qB1, cc[1]);

    float pvv[2][4];
    if (phase != 1) {
      const float eB = (phase == 0) ? eLow : eHigh;
#pragma unroll
      for (int cg = 0; cg < 2; ++cg) {
#pragma unroll
        for (int i = 0; i < 4; ++i) {
          float p = __builtin_amdgcn_exp2f(__builtin_fmaf(cc[cg][i], L2E, eB));
          sSimple += p; pvv[cg][i] = p;
        }
      }
    } else {
      const int kc0 = it * 32;
#pragma unroll
      for (int cg = 0; cg < 2; ++cg) {
        const int krow0 = kc0 + cg * 16 + quad * 4;
        const int dbase = krow0 + 64 - qw0 - l16;
#pragma unroll
        for (int i = 0; i < 4; ++i) {
          int delta = dbase + i;
          delta = delta < 0 ? 0 : (delta > 128 ? 128 : delta);
          const float t = cc[cg][i] + qb[cg][i];
          float p = __builtin_amdgcn_exp2f(__builtin_fmaf(t, L2E, M8));
          if (krow0 + i >= 1500) p = 0.f;
          sDall += p;
          sD0   += (delta == 0)   ? p : 0.f;
          sD128 += (delta == 128) ? p : 0.f;
          if ((delta != 0) & (delta != 128)) pb_row[delta] = f2bf(p);
          pvv[cg][i] = p;
        }
      }
    }

    // P^T pack: store rows q=l16 of P (cols k) as 2x b64, read back as A-fragment
#pragma unroll
    for (int cg = 0; cg < 2; ++cg) {
      uint2 pk;
      pk.x = (uint)f2bf(pvv[cg][0]) | ((uint)f2bf(pvv[cg][1]) << 16);
      pk.y = (uint)f2bf(pvv[cg][2]) | ((uint)f2bf(pvv[cg][3]) << 16);
      *(uint2*)(ps_w + l16 * 40 + cg * 16 + quad * 4) = pk;
    }
    bf16x8 pa = *(const bf16x8*)(ps_w + l16 * 40 + quad * 8);
    accf[0] = MFMA16(pa, vcur.v0, accf[0]);
    accf[1] = MFMA16(pa, vcur.v1, accf[1]);
    accf[2] = MFMA16(pa, vcur.v2, accf[2]);
    accf[3] = MFMA16(pa, vcur.v3, accf[3]);

    if (it < 46) kcur = knext;
  }

  // reduce softmax state over the 4 quads (q = l16 per lane)
  const float sLow = sLowSave;
  const float sHigh = sSimple - sLowSave;
  float lpart = sSimple + sDall;
  float clow = sLow + sD0;
  float chigh = sHigh + sD128;
#pragma unroll
  for (int m = 16; m <= 32; m <<= 1) {
    lpart += __shfl_xor(lpart, m);
    clow  += __shfl_xor(clow, m);
    chigh += __shfl_xor(chigh, m);
  }
  const float linv = 1.0f / lpart;
  float* red = (float*)ps_w;  // P tile dead; reuse per-wave region
  if (quad == 0) { red[l16] = linv; red[16 + l16] = clow; red[32 + l16] = chigh; }

  // o2 = pb[16x128] @ pos_v[128x64] via MFMA (A rows q=l16 from pb, B rows d from posvT)
  f32x4 o2[4];
#pragma unroll
  for (int dc = 0; dc < 4; ++dc) o2[dc] = zf;
  const u16* pbr = pb_s + (w * 16 + l16) * 136;
#pragma unroll
  for (int kk = 0; kk < 4; ++kk) {
    bf16x8 pa2 = *(const bf16x8*)(pbr + kk * 32 + quad * 8);
#pragma unroll
    for (int dc = 0; dc < 4; ++dc) {
      bf16x8 vb2 = *(const bf16x8*)(posvT + (size_t)(dc * 16 + l16) * 136 + kk * 32 + quad * 8);
      o2[dc] = MFMA16(pa2, vb2, o2[dc]);
    }
  }

#pragma unroll
  for (int dc = 0; dc < 4; ++dc) {
    const int d = dc * 16 + l16;
    const float pv0 = posv[d], pv1 = posv[128 * 64 + d];
#pragma unroll
    for (int i = 0; i < 4; ++i) {
      const int qg = qw0 + quad * 4 + i;
      if (qg < 1500) {
        const float li = red[quad * 4 + i];
        const float cl = red[16 + quad * 4 + i];
        const float ch = red[32 + quad * 4 + i];
        const float val = (accf[dc][i] + o2[dc][i] + cl * pv0 + ch * pv1) * li;
        hidden[((size_t)(b * 1500 + qg)) * 1024 + head * 64 + d] = f2bf(val);
      }
    }
  }
}

// ---------------- launcher ----------------
extern "C" void kernel_launch(void* const* d_in, const int* in_sizes, int n_in,
                              void* d_out, int out_size, void* d_ws, size_t ws_size,
                              hipStream_t stream) {
  const float* query = (const float*)d_in[0];
  const float* key   = (const float*)d_in[1];
  const float* value = (const float*)d_in[2];
  const float* Wq = (const float*)d_in[3];
  const float* bq = (const float*)d_in[4];
  const float* Wk = (const float*)d_in[5];
  const float* bk = (const float*)d_in[6];
  const float* Wv = (const float*)d_in[7];
  const float* bv = (const float*)d_in[8];
  const float* posk = (const float*)d_in[9];
  const float* posv = (const float*)d_in[10];
  const float* Wfc = (const float*)d_in[11];
  const float* bfc = (const float*)d_in[12];
  float* out = (float*)d_out;

  char* p = (char*)d_ws;
  u16* X = (u16*)p;        p += 3UL * 6016 * 1024 * 2;   // Xq,Xk,Xv (M padded to 6016)
  u16* Wt = (u16*)p;       p += 3UL * 1024 * 1024 * 2;   // Wq_t,Wk_t,Wv_t
  u16* Wfct = (u16*)p;     p += 1024UL * 1024 * 2;
  u16* poskbf = (u16*)p;   p += 144UL * 64 * 2;
  u16* posvT = (u16*)p;    p += 64UL * 136 * 2;
  float* biascat = (float*)p; p += 3UL * 1024 * 4;
  u16* qkv = (u16*)p;      p += 3UL * 4 * 16 * 1536 * 64 * 2;  // q,k,v [B*NH][1536][64]
  u16* hidden = X;                       // X region dead after QKV GEMM
  u16* Vt = X + 6291456;                 // aliases Xk/Xv region, dead after QKV GEMM

  pack_x_kernel<<<dim3(6000, 1, 3), 256, 0, stream>>>(query, key, value, X);
  pack_misc_kernel<<<dim3(1), 256, 0, stream>>>(bq, bk, bv, posk, posv, biascat, poskbf, posvT);
  pack_wqkv_kernel<<<dim3(16, 16, 3), 256, 0, stream>>>(Wq, Wk, Wv, Wt);
  pack_wfc_kernel<<<dim3(16, 16), 256, 0, stream>>>(Wfc, Wfct);

  gemm_bt_kernel<<<dim3(8, 47, 3), 256, 0, stream>>>(
      X, 6016L * 1024, Wt, 1024L * 1024, biascat, 1024L, qkv, nullptr, 0);

  vtrans_kernel<<<dim3(24, 64), 256, 0, stream>>>(qkv, Vt);

  attn_kernel<<<dim3(24, 16, 4), 256, 0, stream>>>(qkv, Vt, poskbf, posvT, posv, hidden);

  gemm_bt_kernel<<<dim3(8, 47, 1), 256, 0, stream>>>(
      hidden, 0L, Wfct, 0L, bfc, 0L, nullptr, out, 1);
}

// Round 5
// 546.600 us; speedup vs baseline: 1.0017x; 1.0017x over previous
//
#include <hip/hip_runtime.h>
#include <stdint.h>

typedef unsigned short u16;
typedef __attribute__((ext_vector_type(8))) short bf16x8;
typedef __attribute__((ext_vector_type(4))) float f32x4;

#define MFMA16(a, b, c) __builtin_amdgcn_mfma_f32_16x16x32_bf16(a, b, c, 0, 0, 0)

__device__ __forceinline__ u16 f2bf(float x) {
  union { float f; uint32_t u; } v; v.f = x;
  uint32_t r = (v.u + 0x7FFFu + ((v.u >> 16) & 1u)) >> 16;
  return (u16)r;
}
__device__ __forceinline__ float bf2f(u16 h) {
  union { uint32_t u; float f; } v; v.u = ((uint32_t)h) << 16; return v.f;
}
__device__ __forceinline__ void gll16(const void* g, void* s) {
  __builtin_amdgcn_global_load_lds((const __attribute__((address_space(1))) unsigned int*)g,
                                   (__attribute__((address_space(3))) unsigned int*)s, 16, 0, 0);
}

// ---------------- pack kernels ----------------

// grid (6000,1,3), block 256: fp32 -> bf16, 4 elems/thread
__global__ __launch_bounds__(256) void pack_x_kernel(const float* __restrict__ q,
                                                     const float* __restrict__ k,
                                                     const float* __restrict__ v,
                                                     u16* __restrict__ X) {
  const float* src = blockIdx.z == 0 ? q : (blockIdx.z == 1 ? k : v);
  u16* dst = X + (size_t)blockIdx.z * (6016UL * 1024UL);
  size_t idx = (size_t)blockIdx.x * 1024 + (size_t)threadIdx.x * 4;
  float4 f = *(const float4*)(src + idx);
  ushort4 o;
  o.x = f2bf(f.x); o.y = f2bf(f.y); o.z = f2bf(f.z); o.w = f2bf(f.w);
  *(ushort4*)(dst + idx) = o;
}

// 1 block: bias concat + pos_k bf16 (padded 144 rows) + pos_v^T bf16 (64 x 136)
__global__ __launch_bounds__(256) void pack_misc_kernel(const float* __restrict__ bq,
                                                        const float* __restrict__ bk,
                                                        const float* __restrict__ bv,
                                                        const float* __restrict__ posk,
                                                        const float* __restrict__ posv,
                                                        float* __restrict__ biascat,
                                                        u16* __restrict__ poskbf,
                                                        u16* __restrict__ posvT) {
  for (int i = threadIdx.x; i < 1024; i += 256) {
    biascat[i] = bq[i]; biascat[1024 + i] = bk[i]; biascat[2048 + i] = bv[i];
  }
  for (int i = threadIdx.x; i < 144 * 64; i += 256) {
    int r = i >> 6;
    poskbf[i] = (r < 129) ? f2bf(posk[i]) : (u16)0;
  }
  {
    const int d = threadIdx.x & 63, rr = threadIdx.x >> 6;
#pragma unroll
    for (int j = 0; j < 34; ++j) {
      const int r = rr * 34 + j;
      posvT[d * 136 + r] = (r < 129) ? f2bf(posv[(size_t)r * 64 + d]) : (u16)0;
    }
  }
}

// grid (16,16,3): Wt[z][(n*64+d)*1024 + h] = W[z][n][h][d] (bf16)
__global__ __launch_bounds__(256) void pack_wqkv_kernel(const float* __restrict__ Wq,
                                                        const float* __restrict__ Wk,
                                                        const float* __restrict__ Wv,
                                                        u16* __restrict__ Wt) {
  __shared__ float tile[64][65];
  const float* W = blockIdx.z == 0 ? Wq : (blockIdx.z == 1 ? Wk : Wv);
  u16* dst = Wt + (size_t)blockIdx.z * (1024UL * 1024UL);
  const int n = blockIdx.y, h0 = blockIdx.x * 64;
  const int r = threadIdx.x >> 2, c0 = (threadIdx.x & 3) * 16;
  const float* src = W + (size_t)n * 65536 + (size_t)(h0 + r) * 64 + c0;
#pragma unroll
  for (int j = 0; j < 16; j += 4) {
    float4 f = *(const float4*)(src + j);
    tile[r][c0 + j] = f.x; tile[r][c0 + j + 1] = f.y;
    tile[r][c0 + j + 2] = f.z; tile[r][c0 + j + 3] = f.w;
  }
  __syncthreads();
  u16* outp = dst + (size_t)(n * 64 + r) * 1024 + h0 + c0;
#pragma unroll
  for (int j = 0; j < 16; ++j) outp[j] = f2bf(tile[c0 + j][r]);
}

// grid (16,16): Wfct[o*1024 + i] = Wfc[i*1024 + o] (bf16)
__global__ __launch_bounds__(256) void pack_wfc_kernel(const float* __restrict__ Wfc,
                                                       u16* __restrict__ Wfct) {
  __shared__ float tile[64][65];
  const int i0 = blockIdx.x * 64, o0 = blockIdx.y * 64;
  const int r = threadIdx.x >> 2, c0 = (threadIdx.x & 3) * 16;
  const float* src = Wfc + (size_t)(i0 + r) * 1024 + o0 + c0;
#pragma unroll
  for (int j = 0; j < 16; j += 4) {
    float4 f = *(const float4*)(src + j);
    tile[r][c0 + j] = f.x; tile[r][c0 + j + 1] = f.y;
    tile[r][c0 + j + 2] = f.z; tile[r][c0 + j + 3] = f.w;
  }
  __syncthreads();
  u16* outp = Wfct + (size_t)(o0 + r) * 1024 + i0 + c0;
#pragma unroll
  for (int j = 0; j < 16; ++j) outp[j] = f2bf(tile[c0 + j][r]);
}

// grid (1536) 1-D, XCD-swizzled: bh = bi&63 (XCD = bh%8), s-tile = bi>>6.
// transpose V [bh][1536][64] -> Vt [bh][64][1536]
__global__ __launch_bounds__(256) void vtrans_kernel(const u16* __restrict__ qkv,
                                                     u16* __restrict__ Vt) {
  const size_t ZS = 4UL * 16 * 1536 * 64;
  __shared__ u16 t[64][72];
  const int bh = blockIdx.x & 63, s0 = (blockIdx.x >> 6) * 64;
  const u16* src = qkv + 2 * ZS + (size_t)bh * (1536UL * 64UL) + (size_t)s0 * 64;
  const int r = threadIdx.x >> 2, c0 = (threadIdx.x & 3) * 16;
  *(uint4*)&t[r][c0]     = *(const uint4*)(src + (size_t)r * 64 + c0);
  *(uint4*)&t[r][c0 + 8] = *(const uint4*)(src + (size_t)r * 64 + c0 + 8);
  __syncthreads();
  uint4 a, bvec;
  uint tmp[8];
#pragma unroll
  for (int j = 0; j < 8; ++j)
    tmp[j] = (uint)t[c0 + 2 * j][r] | ((uint)t[c0 + 2 * j + 1][r] << 16);
  a.x = tmp[0]; a.y = tmp[1]; a.z = tmp[2]; a.w = tmp[3];
  bvec.x = tmp[4]; bvec.y = tmp[5]; bvec.z = tmp[6]; bvec.w = tmp[7];
  u16* dst = Vt + (size_t)(bh * 64 + r) * 1536 + s0 + c0;
  *(uint4*)dst = a;
  *(uint4*)(dst + 8) = bvec;
}

// ---------------- GEMM: C[m,n] = sum_k A[m,k]*Bt[n,k] (+bias), m97-style ----------------
__global__ __launch_bounds__(256) void gemm_bt_kernel(
    const u16* __restrict__ Abase, long aStride,
    const u16* __restrict__ Bbase, long bStride,
    const float* __restrict__ biasBase, long biasStride,
    u16* __restrict__ outBF, float* __restrict__ outF, int mode) {
  const int z = blockIdx.z;
  const u16* A = Abase + (size_t)z * aStride;
  const u16* Bt = Bbase + (size_t)z * bStride;
  const float* bias = biasBase + (size_t)z * biasStride;
  __shared__ u16 As[128 * 32];
  __shared__ u16 Bs[128 * 32];
  const int tid = threadIdx.x, w = tid >> 6, lane = tid & 63;
  const int quad = lane >> 4, l16 = lane & 15;
  const int wm = w >> 1, wn = w & 1;
  const int m0 = blockIdx.y * 128, n0 = blockIdx.x * 128;
  const int srow = w * 16 + (lane >> 2);
  const int scol = (lane & 3) * 8;
  const u16* gA0 = A + (size_t)(m0 + srow) * 1024 + scol;
  const u16* gA1 = gA0 + 64UL * 1024;
  const u16* gB0 = Bt + (size_t)(n0 + srow) * 1024 + scol;
  const u16* gB1 = gB0 + 64UL * 1024;
  u16* lA0 = As + (w * 16) * 32;
  u16* lA1 = As + (64 + w * 16) * 32;
  u16* lB0 = Bs + (w * 16) * 32;
  u16* lB1 = Bs + (64 + w * 16) * 32;

  f32x4 acc[4][4];
  const f32x4 zf = {0.f, 0.f, 0.f, 0.f};
#pragma unroll
  for (int a = 0; a < 4; ++a)
#pragma unroll
    for (int b = 0; b < 4; ++b) acc[a][b] = zf;

  for (int kt = 0; kt < 32; ++kt) {
    const int k0 = kt * 32;
    gll16(gA0 + k0, lA0);
    gll16(gA1 + k0, lA1);
    gll16(gB0 + k0, lB0);
    gll16(gB1 + k0, lB1);
    __syncthreads();
    bf16x8 af[4], bfr[4];
#pragma unroll
    for (int f = 0; f < 4; ++f) {
      af[f]  = *(const bf16x8*)(As + (wm * 64 + f * 16 + l16) * 32 + quad * 8);
      bfr[f] = *(const bf16x8*)(Bs + (wn * 64 + f * 16 + l16) * 32 + quad * 8);
    }
#pragma unroll
    for (int fm = 0; fm < 4; ++fm)
#pragma unroll
      for (int fn = 0; fn < 4; ++fn)
        acc[fm][fn] = MFMA16(af[fm], bfr[fn], acc[fm][fn]);
    __syncthreads();
  }

  if (mode == 0) {
    const float scale = (z == 0) ? 0.125f : 1.0f;
    u16* out = outBF + (size_t)z * (4UL * 16 * 1536 * 64);
#pragma unroll
    for (int fm = 0; fm < 4; ++fm) {
#pragma unroll
      for (int i = 0; i < 4; ++i) {
        const int m = m0 + wm * 64 + fm * 16 + quad * 4 + i;
        if (m >= 6000) continue;
        const int bb = m / 1500;
        const int s = m - bb * 1500;
#pragma unroll
        for (int fn = 0; fn < 4; ++fn) {
          const int n = n0 + wn * 64 + fn * 16 + l16;
          const float vv = (acc[fm][fn][i] + bias[n]) * scale;
          const int h = n >> 6, d = n & 63;
          out[((size_t)(bb * 16 + h) * 1536 + s) * 64 + d] = f2bf(vv);
        }
      }
    }
  } else {
#pragma unroll
    for (int fm = 0; fm < 4; ++fm) {
#pragma unroll
      for (int i = 0; i < 4; ++i) {
        const int m = m0 + wm * 64 + fm * 16 + quad * 4 + i;
        if (m >= 6000) continue;
#pragma unroll
        for (int fn = 0; fn < 4; ++fn) {
          const int n = n0 + wn * 64 + fn * 16 + l16;
          outF[(size_t)m * 1024 + n] = acc[fm][fn][i] + bias[n];
        }
      }
    }
  }
}

// ---------------- fused attention v4: XCD swizzle + forced unroll-2 pipeline ----------------
// grid (1536) 1-D: bh = bi&63 -> XCD = bh%8 (L2 locality), q-tile = bi>>6.
// block 256 = 4 independent waves; wave w owns q rows [q0+w*16, +16)
// S^T = K.Q^T MFMA layout: lane holds (k = kc+cg*16+quad*4+i, q = qw0+l16)
struct KF { bf16x8 a0, a1, b0, b1; };
struct VF { bf16x8 v0, v1, v2, v3; };

__global__ __launch_bounds__(256)
__attribute__((amdgpu_waves_per_eu(3, 3)))
void attn_kernel(const u16* __restrict__ qkv,
                 const u16* __restrict__ Vt,
                 const u16* __restrict__ poskbf,
                 const u16* __restrict__ posvT,
                 const float* __restrict__ posv,
                 u16* __restrict__ hidden) {
  const size_t ZS = 4UL * 16 * 1536 * 64;
  __shared__ u16 qp_s[64 * 136];   // bf16 qp[q_local][r], per-wave 16-row slabs
  __shared__ u16 pb_s[64 * 136];   // bf16 in-band rel-v histogram [q_local][delta]
  __shared__ u16 p_s[4 * 16 * 40]; // per-wave P^ tile [q][k], pitch 40

  const int tid = threadIdx.x;
  const int w = tid >> 6, lane = tid & 63, quad = lane >> 4, l16 = lane & 15;
  const int bi = blockIdx.x;
  const int bh = bi & 63;          // b*16+head ; XCD = bh & 7
  const int q0 = (bi >> 6) * 64, qw0 = q0 + w * 16;
  const int b = bh >> 4;
  const size_t sb = (size_t)bh * (1536UL * 64UL);
  const u16* Qp = qkv + sb;
  const u16* Kp = qkv + ZS + sb;
  const u16* Vrow = Vt + (size_t)bh * (64UL * 1536UL) + (size_t)l16 * 1536;
  u16* ps_w = p_s + w * 640;
  u16* qp_row = qp_s + (w * 16 + l16) * 136;
  u16* pb_row = pb_s + (w * 16 + l16) * 136;

  // zero own pb slab (wave-private)
  {
    uint* pz = (uint*)(pb_s + w * 16 * 136);
    for (int i = lane; i < 1088; i += 64) pz[i] = 0u;
  }

  // Q fragment (rows q = qw0 + l16)
  const u16* qptr = Qp + (size_t)(qw0 + l16) * 64 + quad * 8;
  const bf16x8 qB0 = *(const bf16x8*)qptr;
  const bf16x8 qB1 = *(const bf16x8*)(qptr + 32);

  // qp[q][r] = q . pos_k[r] via MFMA; C layout: row q_loc = quad*4+i, col r = l16
#pragma unroll
  for (int nf = 0; nf < 9; ++nf) {
    const u16* bp = poskbf + (size_t)(nf * 16 + l16) * 64 + quad * 8;
    bf16x8 b0 = *(const bf16x8*)bp;
    bf16x8 b1 = *(const bf16x8*)(bp + 32);
    f32x4 c = {0.f, 0.f, 0.f, 0.f};
    c = MFMA16(qB0, b0, c);
    c = MFMA16(qB1, b1, c);
    const int col = nf * 16 + l16;
    if (col < 136) {
#pragma unroll
      for (int i = 0; i < 4; ++i)
        qp_s[(w * 16 + quad * 4 + i) * 136 + col] = f2bf(c[i]);
    }
  }
  __syncthreads();

  const float L2E = 1.44269504f;
  const float M8 = -8.0f * L2E;
  const float eLow  = __builtin_fmaf(bf2f(qp_row[0]), L2E, M8);
  const float eHigh = __builtin_fmaf(bf2f(qp_row[128]), L2E, M8);

  f32x4 accf[4];
  const f32x4 zf = {0.f, 0.f, 0.f, 0.f};
#pragma unroll
  for (int dc = 0; dc < 4; ++dc) accf[dc] = zf;
  // low+high share one accumulator; snapshot at the low->diag boundary
  float sSimple = 0.f, sLowSave = 0.f, sDall = 0.f, sD0 = 0.f, sD128 = 0.f;

  const int itLowEnd = (qw0 >= 95) ? (((qw0 - 95) >> 5) + 1) : 0;
  const int itHigh0 = (qw0 + 110) >> 5;
  const int dEnd = itHigh0 < 46 ? itHigh0 : 46;

  auto loadK = [&](int it) {
    KF r;
    const u16* kptr = Kp + (size_t)(it * 32 + l16) * 64 + quad * 8;
    r.a0 = *(const bf16x8*)kptr;
    r.a1 = *(const bf16x8*)(kptr + 32);
    r.b0 = *(const bf16x8*)(kptr + 1024);
    r.b1 = *(const bf16x8*)(kptr + 1056);
    return r;
  };
  auto loadV = [&](int it) {
    VF r;
    const u16* vp = Vrow + it * 32 + quad * 8;
    r.v0 = *(const bf16x8*)vp;
    r.v1 = *(const bf16x8*)(vp + 16 * 1536);
    r.v2 = *(const bf16x8*)(vp + 32 * 1536);
    r.v3 = *(const bf16x8*)(vp + 48 * 1536);
    return r;
  };

  // One k-chunk body (32 k rows). Shares the per-wave p_s slot: DS ops within a
  // wave execute in order, so body A's b128 read completes before body B's
  // writes to the same addresses.
  auto body = [&](int it, const KF& kf, const VF& vf) {
    if (it == itLowEnd) sLowSave = sSimple;
    const int phase = (it < itLowEnd) ? 0 : ((it >= 46) ? 1 : ((it < dEnd) ? 1 : 2));

    float qb[2][4];
    if (phase == 1) {
      const int base = it * 32 + 64 - qw0 - l16;
#pragma unroll
      for (int cg = 0; cg < 2; ++cg) {
#pragma unroll
        for (int i = 0; i < 4; ++i) {
          int delta = base + cg * 16 + quad * 4 + i;
          delta = delta < 0 ? 0 : (delta > 128 ? 128 : delta);
          qb[cg][i] = bf2f(qp_row[delta]);
        }
      }
    }

    f32x4 cc[2];
    cc[0] = zf; cc[1] = zf;
    cc[0] = MFMA16(kf.a0, qB0, cc[0]);
    cc[0] = MFMA16(kf.a1, qB1, cc[0]);
    cc[1] = MFMA16(kf.b0, qB0, cc[1]);
    cc[1] = MFMA16(kf.b1, qB1, cc[1]);

    float pvv[2][4];
    if (phase != 1) {
      const float eB = (phase == 0) ? eLow : eHigh;
#pragma unroll
      for (int cg = 0; cg < 2; ++cg) {
#pragma unroll
        for (int i = 0; i < 4; ++i) {
          float p = __builtin_amdgcn_exp2f(__builtin_fmaf(cc[cg][i], L2E, eB));
          sSimple += p; pvv[cg][i] = p;
        }
      }
    } else {
      const int kc0 = it * 32;
#pragma unroll
      for (int cg = 0; cg < 2; ++cg) {
        const int krow0 = kc0 + cg * 16 + quad * 4;
        const int dbase = krow0 + 64 - qw0 - l16;
#pragma unroll
        for (int i = 0; i < 4; ++i) {
          int delta = dbase + i;
          delta = delta < 0 ? 0 : (delta > 128 ? 128 : delta);
          const float t = cc[cg][i] + qb[cg][i];
          float p = __builtin_amdgcn_exp2f(__builtin_fmaf(t, L2E, M8));
          if (krow0 + i >= 1500) p = 0.f;
          sDall += p;
          sD0   += (delta == 0)   ? p : 0.f;
          sD128 += (delta == 128) ? p : 0.f;
          if ((delta != 0) & (delta != 128)) pb_row[delta] = f2bf(p);
          pvv[cg][i] = p;
        }
      }
    }

#pragma unroll
    for (int cg = 0; cg < 2; ++cg) {
      uint2 pk;
      pk.x = (uint)f2bf(pvv[cg][0]) | ((uint)f2bf(pvv[cg][1]) << 16);
      pk.y = (uint)f2bf(pvv[cg][2]) | ((uint)f2bf(pvv[cg][3]) << 16);
      *(uint2*)(ps_w + l16 * 40 + cg * 16 + quad * 4) = pk;
    }
    bf16x8 pa = *(const bf16x8*)(ps_w + l16 * 40 + quad * 8);
    accf[0] = MFMA16(pa, vf.v0, accf[0]);
    accf[1] = MFMA16(pa, vf.v1, accf[1]);
    accf[2] = MFMA16(pa, vf.v2, accf[2]);
    accf[3] = MFMA16(pa, vf.v3, accf[3]);
  };

  // unroll-2: both iteration chains' loads issued before either consumer
  for (int p2 = 0; p2 < 23; ++p2) {
    const int itA = p2 * 2, itB = itA + 1;
    KF kA = loadK(itA);
    VF vA = loadV(itA);
    KF kB = loadK(itB);
    VF vB = loadV(itB);
    body(itA, kA, vA);
    body(itB, kB, vB);
  }
  {
    KF kT = loadK(46);
    VF vT = loadV(46);
    body(46, kT, vT);
  }

  // reduce softmax state over the 4 quads (q = l16 per lane)
  const float sLow = sLowSave;
  const float sHigh = sSimple - sLowSave;
  float lpart = sSimple + sDall;
  float clow = sLow + sD0;
  float chigh = sHigh + sD128;
#pragma unroll
  for (int m = 16; m <= 32; m <<= 1) {
    lpart += __shfl_xor(lpart, m);
    clow  += __shfl_xor(clow, m);
    chigh += __shfl_xor(chigh, m);
  }
  const float linv = 1.0f / lpart;
  float* red = (float*)ps_w;  // P tile dead; reuse per-wave region
  if (quad == 0) { red[l16] = linv; red[16 + l16] = clow; red[32 + l16] = chigh; }

  // o2 = pb[16x128] @ pos_v[128x64] via MFMA (A rows q=l16 from pb, B rows d from posvT)
  f32x4 o2[4];
#pragma unroll
  for (int dc = 0; dc < 4; ++dc) o2[dc] = zf;
  const u16* pbr = pb_s + (w * 16 + l16) * 136;
#pragma unroll
  for (int kk = 0; kk < 4; ++kk) {
    bf16x8 pa2 = *(const bf16x8*)(pbr + kk * 32 + quad * 8);
#pragma unroll
    for (int dc = 0; dc < 4; ++dc) {
      bf16x8 vb2 = *(const bf16x8*)(posvT + (size_t)(dc * 16 + l16) * 136 + kk * 32 + quad * 8);
      o2[dc] = MFMA16(pa2, vb2, o2[dc]);
    }
  }

#pragma unroll
  for (int dc = 0; dc < 4; ++dc) {
    const int d = dc * 16 + l16;
    const float pv0 = posv[d], pv1 = posv[128 * 64 + d];
#pragma unroll
    for (int i = 0; i < 4; ++i) {
      const int qg = qw0 + quad * 4 + i;
      if (qg < 1500) {
        const float li = red[quad * 4 + i];
        const float cl = red[16 + quad * 4 + i];
        const float ch = red[32 + quad * 4 + i];
        const float val = (accf[dc][i] + o2[dc][i] + cl * pv0 + ch * pv1) * li;
        hidden[((size_t)(b * 1500 + qg)) * 1024 + (bh & 15) * 64 + d] = f2bf(val);
      }
    }
  }
}

// ---------------- launcher ----------------
extern "C" void kernel_launch(void* const* d_in, const int* in_sizes, int n_in,
                              void* d_out, int out_size, void* d_ws, size_t ws_size,
                              hipStream_t stream) {
  const float* query = (const float*)d_in[0];
  const float* key   = (const float*)d_in[1];
  const float* value = (const float*)d_in[2];
  const float* Wq = (const float*)d_in[3];
  const float* bq = (const float*)d_in[4];
  const float* Wk = (const float*)d_in[5];
  const float* bk = (const float*)d_in[6];
  const float* Wv = (const float*)d_in[7];
  const float* bv = (const float*)d_in[8];
  const float* posk = (const float*)d_in[9];
  const float* posv = (const float*)d_in[10];
  const float* Wfc = (const float*)d_in[11];
  const float* bfc = (const float*)d_in[12];
  float* out = (float*)d_out;

  char* p = (char*)d_ws;
  u16* X = (u16*)p;        p += 3UL * 6016 * 1024 * 2;   // Xq,Xk,Xv (M padded to 6016)
  u16* Wt = (u16*)p;       p += 3UL * 1024 * 1024 * 2;   // Wq_t,Wk_t,Wv_t
  u16* Wfct = (u16*)p;     p += 1024UL * 1024 * 2;
  u16* poskbf = (u16*)p;   p += 144UL * 64 * 2;
  u16* posvT = (u16*)p;    p += 64UL * 136 * 2;
  float* biascat = (float*)p; p += 3UL * 1024 * 4;
  u16* qkv = (u16*)p;      p += 3UL * 4 * 16 * 1536 * 64 * 2;  // q,k,v [B*NH][1536][64]
  u16* hidden = X;                       // X region dead after QKV GEMM
  u16* Vt = X + 6291456;                 // aliases Xk/Xv region, dead after QKV GEMM

  pack_x_kernel<<<dim3(6000, 1, 3), 256, 0, stream>>>(query, key, value, X);
  pack_misc_kernel<<<dim3(1), 256, 0, stream>>>(bq, bk, bv, posk, posv, biascat, poskbf, posvT);
  pack_wqkv_kernel<<<dim3(16, 16, 3), 256, 0, stream>>>(Wq, Wk, Wv, Wt);
  pack_wfc_kernel<<<dim3(16, 16), 256, 0, stream>>>(Wfc, Wfct);

  gemm_bt_kernel<<<dim3(8, 47, 3), 256, 0, stream>>>(
      X, 6016L * 1024, Wt, 1024L * 1024, biascat, 1024L, qkv, nullptr, 0);

  vtrans_kernel<<<dim3(1536), 256, 0, stream>>>(qkv, Vt);

  attn_kernel<<<dim3(1536), 256, 0, stream>>>(qkv, Vt, poskbf, posvT, posv, hidden);

  gemm_bt_kernel<<<dim3(8, 47, 1), 256, 0, stream>>>(
      hidden, 0L, Wfct, 0L, bfc, 0L, nullptr, out, 1);
}

// Round 6
// 394.159 us; speedup vs baseline: 1.3891x; 1.3868x over previous
//
#include <hip/hip_runtime.h>
#include <stdint.h>

typedef unsigned short u16;
typedef __attribute__((ext_vector_type(8))) short bf16x8;
typedef __attribute__((ext_vector_type(4))) float f32x4;

#define MFMA16(a, b, c) __builtin_amdgcn_mfma_f32_16x16x32_bf16(a, b, c, 0, 0, 0)

__device__ __forceinline__ u16 f2bf(float x) {
  union { float f; uint32_t u; } v; v.f = x;
  uint32_t r = (v.u + 0x7FFFu + ((v.u >> 16) & 1u)) >> 16;
  return (u16)r;
}
__device__ __forceinline__ float bf2f(u16 h) {
  union { uint32_t u; float f; } v; v.u = ((uint32_t)h) << 16; return v.f;
}
__device__ __forceinline__ void gll16(const void* g, void* s) {
  __builtin_amdgcn_global_load_lds((const __attribute__((address_space(1))) unsigned int*)g,
                                   (__attribute__((address_space(3))) unsigned int*)s, 16, 0, 0);
}

// ---------------- pack kernels ----------------

// grid (6000,1,3), block 256: fp32 -> bf16, 4 elems/thread
__global__ __launch_bounds__(256) void pack_x_kernel(const float* __restrict__ q,
                                                     const float* __restrict__ k,
                                                     const float* __restrict__ v,
                                                     u16* __restrict__ X) {
  const float* src = blockIdx.z == 0 ? q : (blockIdx.z == 1 ? k : v);
  u16* dst = X + (size_t)blockIdx.z * (6016UL * 1024UL);
  size_t idx = (size_t)blockIdx.x * 1024 + (size_t)threadIdx.x * 4;
  float4 f = *(const float4*)(src + idx);
  ushort4 o;
  o.x = f2bf(f.x); o.y = f2bf(f.y); o.z = f2bf(f.z); o.w = f2bf(f.w);
  *(ushort4*)(dst + idx) = o;
}

// 1 block: bias concat + pos_k bf16 (padded 144 rows) + pos_v^T bf16 (64 x 136)
__global__ __launch_bounds__(256) void pack_misc_kernel(const float* __restrict__ bq,
                                                        const float* __restrict__ bk,
                                                        const float* __restrict__ bv,
                                                        const float* __restrict__ posk,
                                                        const float* __restrict__ posv,
                                                        float* __restrict__ biascat,
                                                        u16* __restrict__ poskbf,
                                                        u16* __restrict__ posvT) {
  for (int i = threadIdx.x; i < 1024; i += 256) {
    biascat[i] = bq[i]; biascat[1024 + i] = bk[i]; biascat[2048 + i] = bv[i];
  }
  for (int i = threadIdx.x; i < 144 * 64; i += 256) {
    int r = i >> 6;
    poskbf[i] = (r < 129) ? f2bf(posk[i]) : (u16)0;
  }
  {
    const int d = threadIdx.x & 63, rr = threadIdx.x >> 6;
#pragma unroll
    for (int j = 0; j < 34; ++j) {
      const int r = rr * 34 + j;
      posvT[d * 136 + r] = (r < 129) ? f2bf(posv[(size_t)r * 64 + d]) : (u16)0;
    }
  }
}

// grid (16,16,3): Wt[z][(n*64+d)*1024 + h] = W[z][n][h][d] (bf16)
__global__ __launch_bounds__(256) void pack_wqkv_kernel(const float* __restrict__ Wq,
                                                        const float* __restrict__ Wk,
                                                        const float* __restrict__ Wv,
                                                        u16* __restrict__ Wt) {
  __shared__ float tile[64][65];
  const float* W = blockIdx.z == 0 ? Wq : (blockIdx.z == 1 ? Wk : Wv);
  u16* dst = Wt + (size_t)blockIdx.z * (1024UL * 1024UL);
  const int n = blockIdx.y, h0 = blockIdx.x * 64;
  const int r = threadIdx.x >> 2, c0 = (threadIdx.x & 3) * 16;
  const float* src = W + (size_t)n * 65536 + (size_t)(h0 + r) * 64 + c0;
#pragma unroll
  for (int j = 0; j < 16; j += 4) {
    float4 f = *(const float4*)(src + j);
    tile[r][c0 + j] = f.x; tile[r][c0 + j + 1] = f.y;
    tile[r][c0 + j + 2] = f.z; tile[r][c0 + j + 3] = f.w;
  }
  __syncthreads();
  u16* outp = dst + (size_t)(n * 64 + r) * 1024 + h0 + c0;
#pragma unroll
  for (int j = 0; j < 16; ++j) outp[j] = f2bf(tile[c0 + j][r]);
}

// grid (16,16): Wfct[o*1024 + i] = Wfc[i*1024 + o] (bf16)
__global__ __launch_bounds__(256) void pack_wfc_kernel(const float* __restrict__ Wfc,
                                                       u16* __restrict__ Wfct) {
  __shared__ float tile[64][65];
  const int i0 = blockIdx.x * 64, o0 = blockIdx.y * 64;
  const int r = threadIdx.x >> 2, c0 = (threadIdx.x & 3) * 16;
  const float* src = Wfc + (size_t)(i0 + r) * 1024 + o0 + c0;
#pragma unroll
  for (int j = 0; j < 16; j += 4) {
    float4 f = *(const float4*)(src + j);
    tile[r][c0 + j] = f.x; tile[r][c0 + j + 1] = f.y;
    tile[r][c0 + j + 2] = f.z; tile[r][c0 + j + 3] = f.w;
  }
  __syncthreads();
  u16* outp = Wfct + (size_t)(o0 + r) * 1024 + i0 + c0;
#pragma unroll
  for (int j = 0; j < 16; ++j) outp[j] = f2bf(tile[c0 + j][r]);
}

// grid (1536) 1-D, XCD-swizzled: bh = bi&63 (XCD = bh%8), s-tile = bi>>6.
// transpose V [bh][1536][64] -> Vt [bh][64][1536]
__global__ __launch_bounds__(256) void vtrans_kernel(const u16* __restrict__ qkv,
                                                     u16* __restrict__ Vt) {
  const size_t ZS = 4UL * 16 * 1536 * 64;
  __shared__ u16 t[64][72];
  const int bh = blockIdx.x & 63, s0 = (blockIdx.x >> 6) * 64;
  const u16* src = qkv + 2 * ZS + (size_t)bh * (1536UL * 64UL) + (size_t)s0 * 64;
  const int r = threadIdx.x >> 2, c0 = (threadIdx.x & 3) * 16;
  *(uint4*)&t[r][c0]     = *(const uint4*)(src + (size_t)r * 64 + c0);
  *(uint4*)&t[r][c0 + 8] = *(const uint4*)(src + (size_t)r * 64 + c0 + 8);
  __syncthreads();
  uint4 a, bvec;
  uint tmp[8];
#pragma unroll
  for (int j = 0; j < 8; ++j)
    tmp[j] = (uint)t[c0 + 2 * j][r] | ((uint)t[c0 + 2 * j + 1][r] << 16);
  a.x = tmp[0]; a.y = tmp[1]; a.z = tmp[2]; a.w = tmp[3];
  bvec.x = tmp[4]; bvec.y = tmp[5]; bvec.z = tmp[6]; bvec.w = tmp[7];
  u16* dst = Vt + (size_t)(bh * 64 + r) * 1536 + s0 + c0;
  *(uint4*)dst = a;
  *(uint4*)(dst + 8) = bvec;
}

// ---------------- GEMM: C[m,n] = sum_k A[m,k]*Bt[n,k] (+bias), m97-style ----------------
__global__ __launch_bounds__(256) void gemm_bt_kernel(
    const u16* __restrict__ Abase, long aStride,
    const u16* __restrict__ Bbase, long bStride,
    const float* __restrict__ biasBase, long biasStride,
    u16* __restrict__ outBF, float* __restrict__ outF, int mode) {
  const int z = blockIdx.z;
  const u16* A = Abase + (size_t)z * aStride;
  const u16* Bt = Bbase + (size_t)z * bStride;
  const float* bias = biasBase + (size_t)z * biasStride;
  __shared__ u16 As[128 * 32];
  __shared__ u16 Bs[128 * 32];
  const int tid = threadIdx.x, w = tid >> 6, lane = tid & 63;
  const int quad = lane >> 4, l16 = lane & 15;
  const int wm = w >> 1, wn = w & 1;
  const int m0 = blockIdx.y * 128, n0 = blockIdx.x * 128;
  const int srow = w * 16 + (lane >> 2);
  const int scol = (lane & 3) * 8;
  const u16* gA0 = A + (size_t)(m0 + srow) * 1024 + scol;
  const u16* gA1 = gA0 + 64UL * 1024;
  const u16* gB0 = Bt + (size_t)(n0 + srow) * 1024 + scol;
  const u16* gB1 = gB0 + 64UL * 1024;
  u16* lA0 = As + (w * 16) * 32;
  u16* lA1 = As + (64 + w * 16) * 32;
  u16* lB0 = Bs + (w * 16) * 32;
  u16* lB1 = Bs + (64 + w * 16) * 32;

  f32x4 acc[4][4];
  const f32x4 zf = {0.f, 0.f, 0.f, 0.f};
#pragma unroll
  for (int a = 0; a < 4; ++a)
#pragma unroll
    for (int b = 0; b < 4; ++b) acc[a][b] = zf;

  for (int kt = 0; kt < 32; ++kt) {
    const int k0 = kt * 32;
    gll16(gA0 + k0, lA0);
    gll16(gA1 + k0, lA1);
    gll16(gB0 + k0, lB0);
    gll16(gB1 + k0, lB1);
    __syncthreads();
    bf16x8 af[4], bfr[4];
#pragma unroll
    for (int f = 0; f < 4; ++f) {
      af[f]  = *(const bf16x8*)(As + (wm * 64 + f * 16 + l16) * 32 + quad * 8);
      bfr[f] = *(const bf16x8*)(Bs + (wn * 64 + f * 16 + l16) * 32 + quad * 8);
    }
#pragma unroll
    for (int fm = 0; fm < 4; ++fm)
#pragma unroll
      for (int fn = 0; fn < 4; ++fn)
        acc[fm][fn] = MFMA16(af[fm], bfr[fn], acc[fm][fn]);
    __syncthreads();
  }

  if (mode == 0) {
    const float scale = (z == 0) ? 0.125f : 1.0f;
    u16* out = outBF + (size_t)z * (4UL * 16 * 1536 * 64);
#pragma unroll
    for (int fm = 0; fm < 4; ++fm) {
#pragma unroll
      for (int i = 0; i < 4; ++i) {
        const int m = m0 + wm * 64 + fm * 16 + quad * 4 + i;
        if (m >= 6000) continue;
        const int bb = m / 1500;
        const int s = m - bb * 1500;
#pragma unroll
        for (int fn = 0; fn < 4; ++fn) {
          const int n = n0 + wn * 64 + fn * 16 + l16;
          const float vv = (acc[fm][fn][i] + bias[n]) * scale;
          const int h = n >> 6, d = n & 63;
          out[((size_t)(bb * 16 + h) * 1536 + s) * 64 + d] = f2bf(vv);
        }
      }
    }
  } else {
#pragma unroll
    for (int fm = 0; fm < 4; ++fm) {
#pragma unroll
      for (int i = 0; i < 4; ++i) {
        const int m = m0 + wm * 64 + fm * 16 + quad * 4 + i;
        if (m >= 6000) continue;
#pragma unroll
        for (int fn = 0; fn < 4; ++fn) {
          const int n = n0 + wn * 64 + fn * 16 + l16;
          outF[(size_t)m * 1024 + n] = acc[fm][fn][i] + bias[n];
        }
      }
    }
  }
}

// ---------------- fused attention v5: DMA-staged K/V double buffer ----------------
// grid (1536): bh = bi&63 (XCD = bh%8), q-tile = bi>>6. block 256 = 4 waves;
// wave w owns q rows [q0+16w, +16). S^T = K.Q^T: lane holds (k=cg*16+quad*4+i, q=l16).
// K staged into LDS with per-row XOR chunk swizzle (conflict-free b128 reads);
// V^T staged plain. P C->A transpose via 8 ds_bpermute (no LDS round trip).
__global__ __launch_bounds__(256) void attn_kernel(const u16* __restrict__ qkv,
                                                   const u16* __restrict__ Vt,
                                                   const u16* __restrict__ poskbf,
                                                   const u16* __restrict__ posvT,
                                                   const float* __restrict__ posv,
                                                   u16* __restrict__ hidden) {
  const size_t ZS = 4UL * 16 * 1536 * 64;
  __shared__ u16 qp_s[64 * 136];    // bf16 qp[q_local][r]
  __shared__ u16 pb_s[64 * 136];    // bf16 in-band rel-v histogram [q_local][delta]
  __shared__ u16 kbuf[2][2048];     // K tile 32 rows x 64 d (chunk-swizzled), dbuf
  __shared__ u16 vbuf[2][2048];     // V^T tile 64 d x 32 k, dbuf

  const int tid = threadIdx.x;
  const int w = tid >> 6, lane = tid & 63, quad = lane >> 4, l16 = lane & 15;
  const int bi = blockIdx.x;
  const int bh = bi & 63;
  const int q0 = (bi >> 6) * 64, qw0 = q0 + w * 16;
  const int b = bh >> 4;
  const size_t sb = (size_t)bh * (1536UL * 64UL);
  const u16* Qp = qkv + sb;
  const u16* Kp = qkv + ZS + sb;
  const u16* Vtb = Vt + (size_t)bh * (64UL * 1536UL);
  u16* qp_row = qp_s + (w * 16 + l16) * 136;
  u16* pb_row = pb_s + (w * 16 + l16) * 136;

  // staging lambdas: wave-uniform LDS base + lane*16B (gll16 contract)
  const int r8 = lane >> 3, c8 = lane & 7;            // K: 8 rows x 8 chunks
  const int vr = lane >> 2, vc = lane & 3;            // V: 16 rows x 4 chunks
  auto stageK = [&](int it, int buf) {
    const u16* src = Kp + (size_t)(it * 32 + w * 8 + r8) * 64 + ((c8 ^ r8) * 8);
    gll16(src, &kbuf[buf][w * 512]);
  };
  auto stageV = [&](int it, int buf) {
    const u16* src = Vtb + (size_t)(w * 16 + vr) * 1536 + it * 32 + vc * 8;
    gll16(src, &vbuf[buf][w * 512]);
  };

  // zero own pb slab (wave-private)
  {
    uint* pz = (uint*)(pb_s + w * 16 * 136);
    for (int i = lane; i < 1088; i += 64) pz[i] = 0u;
  }

  stageK(0, 0);
  stageV(0, 0);

  // Q fragment (rows q = qw0 + l16)
  const u16* qptr = Qp + (size_t)(qw0 + l16) * 64 + quad * 8;
  const bf16x8 qB0 = *(const bf16x8*)qptr;
  const bf16x8 qB1 = *(const bf16x8*)(qptr + 32);

  // qp[q][r] = q . pos_k[r] via MFMA; C layout: row q_loc = quad*4+i, col r = l16
  const f32x4 zf = {0.f, 0.f, 0.f, 0.f};
#pragma unroll
  for (int nf = 0; nf < 9; ++nf) {
    const u16* bp = poskbf + (size_t)(nf * 16 + l16) * 64 + quad * 8;
    bf16x8 b0 = *(const bf16x8*)bp;
    bf16x8 b1 = *(const bf16x8*)(bp + 32);
    f32x4 c = zf;
    c = MFMA16(qB0, b0, c);
    c = MFMA16(qB1, b1, c);
    const int col = nf * 16 + l16;
    if (col < 136) {
#pragma unroll
      for (int i = 0; i < 4; ++i)
        qp_s[(w * 16 + quad * 4 + i) * 136 + col] = f2bf(c[i]);
    }
  }
  __syncthreads();   // qp ready AND buf0 DMA drained (vmcnt(0) before barrier)

  const float L2E = 1.44269504f;
  const float M8 = -8.0f * L2E;
  const float eLow  = __builtin_fmaf(bf2f(qp_row[0]), L2E, M8);
  const float eHigh = __builtin_fmaf(bf2f(qp_row[128]), L2E, M8);

  f32x4 accf[4];
#pragma unroll
  for (int dc = 0; dc < 4; ++dc) accf[dc] = zf;
  float sSimple = 0.f, sLowSave = 0.f, sDall = 0.f, sD0 = 0.f, sD128 = 0.f;

  const int itLowEnd = (qw0 >= 95) ? (((qw0 - 95) >> 5) + 1) : 0;
  const int itHigh0 = (qw0 + 110) >> 5;
  const int dEnd = itHigh0 < 46 ? itHigh0 : 46;

  const int kswz = (quad ^ (l16 & 7)) * 8;
  const int kswz4 = ((quad + 4) ^ (l16 & 7)) * 8;
  const int laneLo = ((quad & 1) << 5) + l16;   // source quad 2*(quad&1)
  const bool cgHi = quad >= 2;

  for (int it = 0; it < 47; ++it) {
    const int cur = it & 1;
    if (it < 46) { stageK(it + 1, cur ^ 1); stageV(it + 1, cur ^ 1); }

    if (it == itLowEnd) sLowSave = sSimple;
    const int phase = (it < itLowEnd) ? 0 : ((it >= 46) ? 1 : ((it < dEnd) ? 1 : 2));

    // K fragments from LDS (chunk-swizzled: conflict-minimal)
    const u16* kb = kbuf[cur];
    bf16x8 ka00 = *(const bf16x8*)(kb + l16 * 64 + kswz);
    bf16x8 ka01 = *(const bf16x8*)(kb + l16 * 64 + kswz4);
    bf16x8 ka10 = *(const bf16x8*)(kb + (16 + l16) * 64 + kswz);
    bf16x8 ka11 = *(const bf16x8*)(kb + (16 + l16) * 64 + kswz4);
    // V^T fragments from LDS
    const u16* vbse = vbuf[cur];
    bf16x8 vb0 = *(const bf16x8*)(vbse + l16 * 32 + quad * 8);
    bf16x8 vb1 = *(const bf16x8*)(vbse + (16 + l16) * 32 + quad * 8);
    bf16x8 vb2 = *(const bf16x8*)(vbse + (32 + l16) * 32 + quad * 8);
    bf16x8 vb3 = *(const bf16x8*)(vbse + (48 + l16) * 32 + quad * 8);

    // diag bias LDS reads (index-only dependence)
    float qb[2][4];
    if (phase == 1) {
      const int base = it * 32 + 64 - qw0 - l16;
#pragma unroll
      for (int cg = 0; cg < 2; ++cg) {
#pragma unroll
        for (int i = 0; i < 4; ++i) {
          int delta = base + cg * 16 + quad * 4 + i;
          delta = delta < 0 ? 0 : (delta > 128 ? 128 : delta);
          qb[cg][i] = bf2f(qp_row[delta]);
        }
      }
    }

    f32x4 cc[2];
    cc[0] = zf; cc[1] = zf;
    cc[0] = MFMA16(ka00, qB0, cc[0]);
    cc[0] = MFMA16(ka01, qB1, cc[0]);
    cc[1] = MFMA16(ka10, qB0, cc[1]);
    cc[1] = MFMA16(ka11, qB1, cc[1]);

    float pvv[2][4];
    if (phase != 1) {
      const float eB = (phase == 0) ? eLow : eHigh;
#pragma unroll
      for (int cg = 0; cg < 2; ++cg) {
#pragma unroll
        for (int i = 0; i < 4; ++i) {
          float p = __builtin_amdgcn_exp2f(__builtin_fmaf(cc[cg][i], L2E, eB));
          sSimple += p; pvv[cg][i] = p;
        }
      }
    } else {
      const int kc0 = it * 32;
#pragma unroll
      for (int cg = 0; cg < 2; ++cg) {
        const int krow0 = kc0 + cg * 16 + quad * 4;
        const int dbase = krow0 + 64 - qw0 - l16;
#pragma unroll
        for (int i = 0; i < 4; ++i) {
          int delta = dbase + i;
          delta = delta < 0 ? 0 : (delta > 128 ? 128 : delta);
          const float t = cc[cg][i] + qb[cg][i];
          float p = __builtin_amdgcn_exp2f(__builtin_fmaf(t, L2E, M8));
          if (krow0 + i >= 1500) p = 0.f;
          sDall += p;
          sD0   += (delta == 0)   ? p : 0.f;
          sD128 += (delta == 128) ? p : 0.f;
          if ((delta != 0) & (delta != 128)) pb_row[delta] = f2bf(p);
          pvv[cg][i] = p;
        }
      }
    }

    // P^T C-layout -> A-layout via lane permute (no LDS round trip).
    // target lane (l16,quad) reg j: src lane = l16 + 16*(2(quad&1) + (j>>2)),
    // src reg = cc[quad>>1][j&3].
    const uint u00 = (uint)f2bf(pvv[0][0]) | ((uint)f2bf(pvv[0][1]) << 16);
    const uint u01 = (uint)f2bf(pvv[0][2]) | ((uint)f2bf(pvv[0][3]) << 16);
    const uint u10 = (uint)f2bf(pvv[1][0]) | ((uint)f2bf(pvv[1][1]) << 16);
    const uint u11 = (uint)f2bf(pvv[1][2]) | ((uint)f2bf(pvv[1][3]) << 16);
    const uint lo00 = __shfl(u00, laneLo),      lo01 = __shfl(u01, laneLo);
    const uint lo10 = __shfl(u10, laneLo),      lo11 = __shfl(u11, laneLo);
    const uint hi00 = __shfl(u00, laneLo + 16), hi01 = __shfl(u01, laneLo + 16);
    const uint hi10 = __shfl(u10, laneLo + 16), hi11 = __shfl(u11, laneLo + 16);
    union { uint u[4]; bf16x8 v; } pa;
    pa.u[0] = cgHi ? lo10 : lo00;
    pa.u[1] = cgHi ? lo11 : lo01;
    pa.u[2] = cgHi ? hi10 : hi00;
    pa.u[3] = cgHi ? hi11 : hi01;

    accf[0] = MFMA16(pa.v, vb0, accf[0]);
    accf[1] = MFMA16(pa.v, vb1, accf[1]);
    accf[2] = MFMA16(pa.v, vb2, accf[2]);
    accf[3] = MFMA16(pa.v, vb3, accf[3]);

    __syncthreads();   // drains next-buffer DMA; guards buffer turnover
  }

  // reduce softmax state over the 4 quads (q = l16 per lane); butterfly gives all lanes
  const float sLow = sLowSave;
  const float sHigh = sSimple - sLowSave;
  float lpart = sSimple + sDall;
  float clow = sLow + sD0;
  float chigh = sHigh + sD128;
#pragma unroll
  for (int m = 16; m <= 32; m <<= 1) {
    lpart += __shfl_xor(lpart, m);
    clow  += __shfl_xor(clow, m);
    chigh += __shfl_xor(chigh, m);
  }
  const float linv = 1.0f / lpart;

  // o2 = pb[16x128] @ pos_v[128x64] via MFMA
  f32x4 o2[4];
#pragma unroll
  for (int dc = 0; dc < 4; ++dc) o2[dc] = zf;
  const u16* pbr = pb_s + (w * 16 + l16) * 136;
#pragma unroll
  for (int kk = 0; kk < 4; ++kk) {
    bf16x8 pa2 = *(const bf16x8*)(pbr + kk * 32 + quad * 8);
#pragma unroll
    for (int dc = 0; dc < 4; ++dc) {
      bf16x8 vb2r = *(const bf16x8*)(posvT + (size_t)(dc * 16 + l16) * 136 + kk * 32 + quad * 8);
      o2[dc] = MFMA16(pa2, vb2r, o2[dc]);
    }
  }

  // per-q scalars live at lane l16=q_loc (any quad after butterfly) -> shfl from lane q_loc
  float li[4], cl[4], ch[4];
#pragma unroll
  for (int i = 0; i < 4; ++i) {
    const int srcl = quad * 4 + i;
    li[i] = __shfl(linv, srcl);
    cl[i] = __shfl(clow, srcl);
    ch[i] = __shfl(chigh, srcl);
  }

#pragma unroll
  for (int dc = 0; dc < 4; ++dc) {
    const int d = dc * 16 + l16;
    const float pv0 = posv[d], pv1 = posv[128 * 64 + d];
#pragma unroll
    for (int i = 0; i < 4; ++i) {
      const int qg = qw0 + quad * 4 + i;
      if (qg < 1500) {
        const float val = (accf[dc][i] + o2[dc][i] + cl[i] * pv0 + ch[i] * pv1) * li[i];
        hidden[((size_t)(b * 1500 + qg)) * 1024 + (bh & 15) * 64 + d] = f2bf(val);
      }
    }
  }
}

// ---------------- launcher ----------------
extern "C" void kernel_launch(void* const* d_in, const int* in_sizes, int n_in,
                              void* d_out, int out_size, void* d_ws, size_t ws_size,
                              hipStream_t stream) {
  const float* query = (const float*)d_in[0];
  const float* key   = (const float*)d_in[1];
  const float* value = (const float*)d_in[2];
  const float* Wq = (const float*)d_in[3];
  const float* bq = (const float*)d_in[4];
  const float* Wk = (const float*)d_in[5];
  const float* bk = (const float*)d_in[6];
  const float* Wv = (const float*)d_in[7];
  const float* bv = (const float*)d_in[8];
  const float* posk = (const float*)d_in[9];
  const float* posv = (const float*)d_in[10];
  const float* Wfc = (const float*)d_in[11];
  const float* bfc = (const float*)d_in[12];
  float* out = (float*)d_out;

  char* p = (char*)d_ws;
  u16* X = (u16*)p;        p += 3UL * 6016 * 1024 * 2;   // Xq,Xk,Xv (M padded to 6016)
  u16* Wt = (u16*)p;       p += 3UL * 1024 * 1024 * 2;   // Wq_t,Wk_t,Wv_t
  u16* Wfct = (u16*)p;     p += 1024UL * 1024 * 2;
  u16* poskbf = (u16*)p;   p += 144UL * 64 * 2;
  u16* posvT = (u16*)p;    p += 64UL * 136 * 2;
  float* biascat = (float*)p; p += 3UL * 1024 * 4;
  u16* qkv = (u16*)p;      p += 3UL * 4 * 16 * 1536 * 64 * 2;  // q,k,v [B*NH][1536][64]
  u16* hidden = X;                       // X region dead after QKV GEMM
  u16* Vt = X + 6291456;                 // aliases Xk/Xv region, dead after QKV GEMM

  pack_x_kernel<<<dim3(6000, 1, 3), 256, 0, stream>>>(query, key, value, X);
  pack_misc_kernel<<<dim3(1), 256, 0, stream>>>(bq, bk, bv, posk, posv, biascat, poskbf, posvT);
  pack_wqkv_kernel<<<dim3(16, 16, 3), 256, 0, stream>>>(Wq, Wk, Wv, Wt);
  pack_wfc_kernel<<<dim3(16, 16), 256, 0, stream>>>(Wfc, Wfct);

  gemm_bt_kernel<<<dim3(8, 47, 3), 256, 0, stream>>>(
      X, 6016L * 1024, Wt, 1024L * 1024, biascat, 1024L, qkv, nullptr, 0);

  vtrans_kernel<<<dim3(1536), 256, 0, stream>>>(qkv, Vt);

  attn_kernel<<<dim3(1536), 256, 0, stream>>>(qkv, Vt, poskbf, posvT, posv, hidden);

  gemm_bt_kernel<<<dim3(8, 47, 1), 256, 0, stream>>>(
      hidden, 0L, Wfct, 0L, bfc, 0L, nullptr, out, 1);
}

// Round 7
// 382.783 us; speedup vs baseline: 1.4304x; 1.0297x over previous
//
#include <hip/hip_runtime.h>
#include <stdint.h>

typedef unsigned short u16;
typedef __attribute__((ext_vector_type(8))) short bf16x8;
typedef __attribute__((ext_vector_type(4))) float f32x4;

#define MFMA16(a, b, c) __builtin_amdgcn_mfma_f32_16x16x32_bf16(a, b, c, 0, 0, 0)

__device__ __forceinline__ u16 f2bf(float x) {
  union { float f; uint32_t u; } v; v.f = x;
  uint32_t r = (v.u + 0x7FFFu + ((v.u >> 16) & 1u)) >> 16;
  return (u16)r;
}
__device__ __forceinline__ float bf2f(u16 h) {
  union { uint32_t u; float f; } v; v.u = ((uint32_t)h) << 16; return v.f;
}
// packed RNE f32x2 -> bf16x2 (gfx942+ VOP3; low16 = a, high16 = b)
__device__ __forceinline__ uint cvt_pk_bf16(float a, float b) {
  uint r;
  asm("v_cvt_pk_bf16_f32 %0, %1, %2" : "=v"(r) : "v"(a), "v"(b));
  return r;
}
__device__ __forceinline__ void gll16(const void* g, void* s) {
  __builtin_amdgcn_global_load_lds((const __attribute__((address_space(1))) unsigned int*)g,
                                   (__attribute__((address_space(3))) unsigned int*)s, 16, 0, 0);
}

// ---------------- pack kernels ----------------

// grid (6000,1,3), block 256: fp32 -> bf16, 4 elems/thread
__global__ __launch_bounds__(256) void pack_x_kernel(const float* __restrict__ q,
                                                     const float* __restrict__ k,
                                                     const float* __restrict__ v,
                                                     u16* __restrict__ X) {
  const float* src = blockIdx.z == 0 ? q : (blockIdx.z == 1 ? k : v);
  u16* dst = X + (size_t)blockIdx.z * (6016UL * 1024UL);
  size_t idx = (size_t)blockIdx.x * 1024 + (size_t)threadIdx.x * 4;
  float4 f = *(const float4*)(src + idx);
  uint2 o;
  o.x = cvt_pk_bf16(f.x, f.y);
  o.y = cvt_pk_bf16(f.z, f.w);
  *(uint2*)(dst + idx) = o;
}

// merged weight/misc pack, grid 1025 blocks:
//  [0,768):    Wt[z][(n*64+d)*1024 + h] = W[z][n][h][d]
//  [768,1024): Wfct[o*1024 + i] = Wfc[i*1024 + o]
//  1024:       bias concat + pos_k bf16 (144 rows) + pos_v^T bf16 (64x136)
__global__ __launch_bounds__(256) void pack_w_kernel(const float* __restrict__ Wq,
                                                     const float* __restrict__ Wk,
                                                     const float* __restrict__ Wv,
                                                     const float* __restrict__ Wfc,
                                                     const float* __restrict__ bq,
                                                     const float* __restrict__ bk,
                                                     const float* __restrict__ bv,
                                                     const float* __restrict__ posk,
                                                     const float* __restrict__ posv,
                                                     u16* __restrict__ Wt,
                                                     u16* __restrict__ Wfct,
                                                     float* __restrict__ biascat,
                                                     u16* __restrict__ poskbf,
                                                     u16* __restrict__ posvT) {
  __shared__ float tile[64][65];
  const int bi = blockIdx.x;
  if (bi == 1024) {
    for (int i = threadIdx.x; i < 1024; i += 256) {
      biascat[i] = bq[i]; biascat[1024 + i] = bk[i]; biascat[2048 + i] = bv[i];
    }
    for (int i = threadIdx.x; i < 144 * 64; i += 256) {
      int r = i >> 6;
      poskbf[i] = (r < 129) ? f2bf(posk[i]) : (u16)0;
    }
    const int d = threadIdx.x & 63, rr = threadIdx.x >> 6;
#pragma unroll
    for (int j = 0; j < 34; ++j) {
      const int r = rr * 34 + j;
      posvT[d * 136 + r] = (r < 129) ? f2bf(posv[(size_t)r * 64 + d]) : (u16)0;
    }
    return;
  }
  const int r = threadIdx.x >> 2, c0 = (threadIdx.x & 3) * 16;
  const float* src;
  u16* outp;
  if (bi < 768) {
    const int z = bi >> 8, rem = bi & 255, n = rem >> 4, h0 = (rem & 15) * 64;
    const float* W = z == 0 ? Wq : (z == 1 ? Wk : Wv);
    src = W + (size_t)n * 65536 + (size_t)(h0 + r) * 64 + c0;
    outp = Wt + (size_t)z * (1024UL * 1024UL) + (size_t)(n * 64 + r) * 1024 + h0 + c0;
  } else {
    const int t = bi - 768;
    const int i0 = (t & 15) * 64, o0 = (t >> 4) * 64;
    src = Wfc + (size_t)(i0 + r) * 1024 + o0 + c0;
    outp = Wfct + (size_t)(o0 + r) * 1024 + i0 + c0;
  }
#pragma unroll
  for (int j = 0; j < 16; j += 4) {
    float4 f = *(const float4*)(src + j);
    tile[r][c0 + j] = f.x; tile[r][c0 + j + 1] = f.y;
    tile[r][c0 + j + 2] = f.z; tile[r][c0 + j + 3] = f.w;
  }
  __syncthreads();
#pragma unroll
  for (int j = 0; j < 16; ++j) outp[j] = f2bf(tile[c0 + j][r]);
}

// grid (1536) 1-D, XCD-swizzled: bh = bi&63 (XCD = bh%8), s-tile = bi>>6.
// transpose V [bh][1536][64] -> Vt [bh][64][1536]
__global__ __launch_bounds__(256) void vtrans_kernel(const u16* __restrict__ qkv,
                                                     u16* __restrict__ Vt) {
  const size_t ZS = 4UL * 16 * 1536 * 64;
  __shared__ u16 t[64][72];
  const int bh = blockIdx.x & 63, s0 = (blockIdx.x >> 6) * 64;
  const u16* src = qkv + 2 * ZS + (size_t)bh * (1536UL * 64UL) + (size_t)s0 * 64;
  const int r = threadIdx.x >> 2, c0 = (threadIdx.x & 3) * 16;
  *(uint4*)&t[r][c0]     = *(const uint4*)(src + (size_t)r * 64 + c0);
  *(uint4*)&t[r][c0 + 8] = *(const uint4*)(src + (size_t)r * 64 + c0 + 8);
  __syncthreads();
  uint4 a, bvec;
  uint tmp[8];
#pragma unroll
  for (int j = 0; j < 8; ++j)
    tmp[j] = (uint)t[c0 + 2 * j][r] | ((uint)t[c0 + 2 * j + 1][r] << 16);
  a.x = tmp[0]; a.y = tmp[1]; a.z = tmp[2]; a.w = tmp[3];
  bvec.x = tmp[4]; bvec.y = tmp[5]; bvec.z = tmp[6]; bvec.w = tmp[7];
  u16* dst = Vt + (size_t)(bh * 64 + r) * 1536 + s0 + c0;
  *(uint4*)dst = a;
  *(uint4*)(dst + 8) = bvec;
}

// ---------------- GEMM: C[m,n] = sum_k A[m,k]*Bt[n,k] (+bias), m97-style ----------------
__global__ __launch_bounds__(256) void gemm_bt_kernel(
    const u16* __restrict__ Abase, long aStride,
    const u16* __restrict__ Bbase, long bStride,
    const float* __restrict__ biasBase, long biasStride,
    u16* __restrict__ outBF, float* __restrict__ outF, int mode) {
  const int z = blockIdx.z;
  const u16* A = Abase + (size_t)z * aStride;
  const u16* Bt = Bbase + (size_t)z * bStride;
  const float* bias = biasBase + (size_t)z * biasStride;
  __shared__ u16 As[128 * 32];
  __shared__ u16 Bs[128 * 32];
  const int tid = threadIdx.x, w = tid >> 6, lane = tid & 63;
  const int quad = lane >> 4, l16 = lane & 15;
  const int wm = w >> 1, wn = w & 1;
  const int m0 = blockIdx.y * 128, n0 = blockIdx.x * 128;
  const int srow = w * 16 + (lane >> 2);
  const int scol = (lane & 3) * 8;
  const u16* gA0 = A + (size_t)(m0 + srow) * 1024 + scol;
  const u16* gA1 = gA0 + 64UL * 1024;
  const u16* gB0 = Bt + (size_t)(n0 + srow) * 1024 + scol;
  const u16* gB1 = gB0 + 64UL * 1024;
  u16* lA0 = As + (w * 16) * 32;
  u16* lA1 = As + (64 + w * 16) * 32;
  u16* lB0 = Bs + (w * 16) * 32;
  u16* lB1 = Bs + (64 + w * 16) * 32;

  f32x4 acc[4][4];
  const f32x4 zf = {0.f, 0.f, 0.f, 0.f};
#pragma unroll
  for (int a = 0; a < 4; ++a)
#pragma unroll
    for (int b = 0; b < 4; ++b) acc[a][b] = zf;

  for (int kt = 0; kt < 32; ++kt) {
    const int k0 = kt * 32;
    gll16(gA0 + k0, lA0);
    gll16(gA1 + k0, lA1);
    gll16(gB0 + k0, lB0);
    gll16(gB1 + k0, lB1);
    __syncthreads();
    bf16x8 af[4], bfr[4];
#pragma unroll
    for (int f = 0; f < 4; ++f) {
      af[f]  = *(const bf16x8*)(As + (wm * 64 + f * 16 + l16) * 32 + quad * 8);
      bfr[f] = *(const bf16x8*)(Bs + (wn * 64 + f * 16 + l16) * 32 + quad * 8);
    }
#pragma unroll
    for (int fm = 0; fm < 4; ++fm)
#pragma unroll
      for (int fn = 0; fn < 4; ++fn)
        acc[fm][fn] = MFMA16(af[fm], bfr[fn], acc[fm][fn]);
    __syncthreads();
  }

  if (mode == 0) {
    const float scale = (z == 0) ? 0.125f : 1.0f;
    u16* out = outBF + (size_t)z * (4UL * 16 * 1536 * 64);
#pragma unroll
    for (int fm = 0; fm < 4; ++fm) {
#pragma unroll
      for (int i = 0; i < 4; ++i) {
        const int m = m0 + wm * 64 + fm * 16 + quad * 4 + i;
        if (m >= 6000) continue;
        const int bb = m / 1500;
        const int s = m - bb * 1500;
#pragma unroll
        for (int fn = 0; fn < 4; ++fn) {
          const int n = n0 + wn * 64 + fn * 16 + l16;
          const float vv = (acc[fm][fn][i] + bias[n]) * scale;
          const int h = n >> 6, d = n & 63;
          out[((size_t)(bb * 16 + h) * 1536 + s) * 64 + d] = f2bf(vv);
        }
      }
    }
  } else {
#pragma unroll
    for (int fm = 0; fm < 4; ++fm) {
#pragma unroll
      for (int i = 0; i < 4; ++i) {
        const int m = m0 + wm * 64 + fm * 16 + quad * 4 + i;
        if (m >= 6000) continue;
#pragma unroll
        for (int fn = 0; fn < 4; ++fn) {
          const int n = n0 + wn * 64 + fn * 16 + l16;
          outF[(size_t)m * 1024 + n] = acc[fm][fn][i] + bias[n];
        }
      }
    }
  }
}

// ---------------- fused attention v6: DMA dbuf + V bank swizzle + cvt_pk ----------------
// grid (1536): bh = bi&63 (XCD = bh%8), q-tile = bi>>6. block 256 = 4 waves;
// wave w owns q rows [q0+16w, +16). S^T = K.Q^T: lane holds (k=cg*16+quad*4+i, q=l16).
// K staged with chunk XOR r8 (2-way = free); V^T staged with chunk XOR (vr>>1)&3
// (2-way = free; was 8-way in r6). P C->A transpose via 8 bpermute.
__global__ __launch_bounds__(256) void attn_kernel(const u16* __restrict__ qkv,
                                                   const u16* __restrict__ Vt,
                                                   const u16* __restrict__ poskbf,
                                                   const u16* __restrict__ posvT,
                                                   const float* __restrict__ posv,
                                                   u16* __restrict__ hidden) {
  const size_t ZS = 4UL * 16 * 1536 * 64;
  __shared__ u16 qp_s[64 * 136];    // bf16 qp[q_local][r]
  __shared__ u16 pb_s[64 * 136];    // bf16 in-band rel-v histogram [q_local][delta]
  __shared__ u16 kbuf[2][2048];     // K tile 32 rows x 64 d (chunk-swizzled), dbuf
  __shared__ u16 vbuf[2][2048];     // V^T tile 64 d x 32 k (chunk-swizzled), dbuf

  const int tid = threadIdx.x;
  const int w = tid >> 6, lane = tid & 63, quad = lane >> 4, l16 = lane & 15;
  const int bi = blockIdx.x;
  const int bh = bi & 63;
  const int q0 = (bi >> 6) * 64, qw0 = q0 + w * 16;
  const int b = bh >> 4;
  const size_t sb = (size_t)bh * (1536UL * 64UL);
  const u16* Qp = qkv + sb;
  const u16* Kp = qkv + ZS + sb;
  const u16* Vtb = Vt + (size_t)bh * (64UL * 1536UL);
  u16* qp_row = qp_s + (w * 16 + l16) * 136;
  u16* pb_row = pb_s + (w * 16 + l16) * 136;

  // staging: wave-uniform LDS base + lane*16B (gll16 contract)
  const int r8 = lane >> 3, c8 = lane & 7;            // K: 8 rows x 8 chunks
  const int vr = lane >> 2, vc = lane & 3;            // V: 16 rows x 4 chunks
  auto stageK = [&](int it, int buf) {
    const u16* src = Kp + (size_t)(it * 32 + w * 8 + r8) * 64 + ((c8 ^ r8) * 8);
    gll16(src, &kbuf[buf][w * 512]);
  };
  auto stageV = [&](int it, int buf) {
    const u16* src = Vtb + (size_t)(w * 16 + vr) * 1536 + it * 32 + ((vc ^ ((vr >> 1) & 3)) * 8);
    gll16(src, &vbuf[buf][w * 512]);
  };

  // zero own pb slab (wave-private)
  {
    uint* pz = (uint*)(pb_s + w * 16 * 136);
    for (int i = lane; i < 1088; i += 64) pz[i] = 0u;
  }

  stageK(0, 0);
  stageV(0, 0);

  // Q fragment (rows q = qw0 + l16)
  const u16* qptr = Qp + (size_t)(qw0 + l16) * 64 + quad * 8;
  const bf16x8 qB0 = *(const bf16x8*)qptr;
  const bf16x8 qB1 = *(const bf16x8*)(qptr + 32);

  // qp[q][r] = q . pos_k[r] via MFMA; C layout: row q_loc = quad*4+i, col r = l16
  const f32x4 zf = {0.f, 0.f, 0.f, 0.f};
#pragma unroll
  for (int nf = 0; nf < 9; ++nf) {
    const u16* bp = poskbf + (size_t)(nf * 16 + l16) * 64 + quad * 8;
    bf16x8 b0 = *(const bf16x8*)bp;
    bf16x8 b1 = *(const bf16x8*)(bp + 32);
    f32x4 c = zf;
    c = MFMA16(qB0, b0, c);
    c = MFMA16(qB1, b1, c);
    const int col = nf * 16 + l16;
    if (col < 136) {
#pragma unroll
      for (int i = 0; i < 4; ++i)
        qp_s[(w * 16 + quad * 4 + i) * 136 + col] = f2bf(c[i]);
    }
  }
  __syncthreads();   // qp ready AND buf0 DMA drained

  const float L2E = 1.44269504f;
  const float M8 = -8.0f * L2E;
  const float eLow  = __builtin_fmaf(bf2f(qp_row[0]), L2E, M8);
  const float eHigh = __builtin_fmaf(bf2f(qp_row[128]), L2E, M8);

  f32x4 accf[4];
#pragma unroll
  for (int dc = 0; dc < 4; ++dc) accf[dc] = zf;
  float sSimple = 0.f, sLowSave = 0.f, sDall = 0.f, sD0 = 0.f, sD128 = 0.f;

  const int itLowEnd = (qw0 >= 95) ? (((qw0 - 95) >> 5) + 1) : 0;
  const int itHigh0 = (qw0 + 110) >> 5;
  const int dEnd = itHigh0 < 46 ? itHigh0 : 46;

  const int kswz = (quad ^ (l16 & 7)) * 8;
  const int kswz4 = ((quad + 4) ^ (l16 & 7)) * 8;
  const int vpos = (quad ^ ((l16 >> 1) & 3)) * 8;   // V chunk position after swizzle
  const int laneLo = ((quad & 1) << 5) + l16;       // source quad 2*(quad&1)
  const bool cgHi = quad >= 2;

  for (int it = 0; it < 47; ++it) {
    const int cur = it & 1;
    if (it < 46) { stageK(it + 1, cur ^ 1); stageV(it + 1, cur ^ 1); }

    if (it == itLowEnd) sLowSave = sSimple;
    const int phase = (it < itLowEnd) ? 0 : ((it >= 46) ? 1 : ((it < dEnd) ? 1 : 2));

    // K fragments (chunk-swizzled, conflict-free)
    const u16* kb = kbuf[cur];
    bf16x8 ka00 = *(const bf16x8*)(kb + l16 * 64 + kswz);
    bf16x8 ka01 = *(const bf16x8*)(kb + l16 * 64 + kswz4);
    bf16x8 ka10 = *(const bf16x8*)(kb + (16 + l16) * 64 + kswz);
    bf16x8 ka11 = *(const bf16x8*)(kb + (16 + l16) * 64 + kswz4);
    // V^T fragments (chunk-swizzled, conflict-free)
    const u16* vbse = vbuf[cur];
    bf16x8 vb0 = *(const bf16x8*)(vbse + l16 * 32 + vpos);
    bf16x8 vb1 = *(const bf16x8*)(vbse + (16 + l16) * 32 + vpos);
    bf16x8 vb2 = *(const bf16x8*)(vbse + (32 + l16) * 32 + vpos);
    bf16x8 vb3 = *(const bf16x8*)(vbse + (48 + l16) * 32 + vpos);

    // diag bias LDS reads (index-only dependence)
    float qb[2][4];
    if (phase == 1) {
      const int base = it * 32 + 64 - qw0 - l16;
#pragma unroll
      for (int cg = 0; cg < 2; ++cg) {
#pragma unroll
        for (int i = 0; i < 4; ++i) {
          int delta = base + cg * 16 + quad * 4 + i;
          delta = delta < 0 ? 0 : (delta > 128 ? 128 : delta);
          qb[cg][i] = bf2f(qp_row[delta]);
        }
      }
    }

    f32x4 cc[2];
    cc[0] = zf; cc[1] = zf;
    cc[0] = MFMA16(ka00, qB0, cc[0]);
    cc[0] = MFMA16(ka01, qB1, cc[0]);
    cc[1] = MFMA16(ka10, qB0, cc[1]);
    cc[1] = MFMA16(ka11, qB1, cc[1]);

    float pvv[2][4];
    if (phase != 1) {
      const float eB = (phase == 0) ? eLow : eHigh;
#pragma unroll
      for (int cg = 0; cg < 2; ++cg) {
#pragma unroll
        for (int i = 0; i < 4; ++i) {
          float p = __builtin_amdgcn_exp2f(__builtin_fmaf(cc[cg][i], L2E, eB));
          sSimple += p; pvv[cg][i] = p;
        }
      }
    } else {
      const int kc0 = it * 32;
#pragma unroll
      for (int cg = 0; cg < 2; ++cg) {
        const int krow0 = kc0 + cg * 16 + quad * 4;
        const int dbase = krow0 + 64 - qw0 - l16;
#pragma unroll
        for (int i = 0; i < 4; ++i) {
          int delta = dbase + i;
          delta = delta < 0 ? 0 : (delta > 128 ? 128 : delta);
          const float t = cc[cg][i] + qb[cg][i];
          float p = __builtin_amdgcn_exp2f(__builtin_fmaf(t, L2E, M8));
          if (krow0 + i >= 1500) p = 0.f;
          sDall += p;
          sD0   += (delta == 0)   ? p : 0.f;
          sD128 += (delta == 128) ? p : 0.f;
          pvv[cg][i] = p;
        }
        // packed bf16 for the pb stores
        const uint pk01 = cvt_pk_bf16(pvv[cg][0], pvv[cg][1]);
        const uint pk23 = cvt_pk_bf16(pvv[cg][2], pvv[cg][3]);
        const u16 hb[4] = {(u16)pk01, (u16)(pk01 >> 16), (u16)pk23, (u16)(pk23 >> 16)};
#pragma unroll
        for (int i = 0; i < 4; ++i) {
          int delta = dbase + i;
          delta = delta < 0 ? 0 : (delta > 128 ? 128 : delta);
          if ((delta != 0) & (delta != 128)) pb_row[delta] = hb[i];
        }
      }
    }

    // P^T C-layout -> A-layout via lane permute (packed with cvt_pk)
    const uint u00 = cvt_pk_bf16(pvv[0][0], pvv[0][1]);
    const uint u01 = cvt_pk_bf16(pvv[0][2], pvv[0][3]);
    const uint u10 = cvt_pk_bf16(pvv[1][0], pvv[1][1]);
    const uint u11 = cvt_pk_bf16(pvv[1][2], pvv[1][3]);
    const uint lo00 = __shfl(u00, laneLo),      lo01 = __shfl(u01, laneLo);
    const uint lo10 = __shfl(u10, laneLo),      lo11 = __shfl(u11, laneLo);
    const uint hi00 = __shfl(u00, laneLo + 16), hi01 = __shfl(u01, laneLo + 16);
    const uint hi10 = __shfl(u10, laneLo + 16), hi11 = __shfl(u11, laneLo + 16);
    union { uint u[4]; bf16x8 v; } pa;
    pa.u[0] = cgHi ? lo10 : lo00;
    pa.u[1] = cgHi ? lo11 : lo01;
    pa.u[2] = cgHi ? hi10 : hi00;
    pa.u[3] = cgHi ? hi11 : hi01;

    accf[0] = MFMA16(pa.v, vb0, accf[0]);
    accf[1] = MFMA16(pa.v, vb1, accf[1]);
    accf[2] = MFMA16(pa.v, vb2, accf[2]);
    accf[3] = MFMA16(pa.v, vb3, accf[3]);

    __syncthreads();   // drains next-buffer DMA; guards buffer turnover
  }

  // reduce softmax state over the 4 quads (q = l16 per lane)
  const float sLow = sLowSave;
  const float sHigh = sSimple - sLowSave;
  float lpart = sSimple + sDall;
  float clow = sLow + sD0;
  float chigh = sHigh + sD128;
#pragma unroll
  for (int m = 16; m <= 32; m <<= 1) {
    lpart += __shfl_xor(lpart, m);
    clow  += __shfl_xor(clow, m);
    chigh += __shfl_xor(chigh, m);
  }
  const float linv = 1.0f / lpart;

  // o2 = pb[16x128] @ pos_v[128x64] via MFMA
  f32x4 o2[4];
#pragma unroll
  for (int dc = 0; dc < 4; ++dc) o2[dc] = zf;
  const u16* pbr = pb_s + (w * 16 + l16) * 136;
#pragma unroll
  for (int kk = 0; kk < 4; ++kk) {
    bf16x8 pa2 = *(const bf16x8*)(pbr + kk * 32 + quad * 8);
#pragma unroll
    for (int dc = 0; dc < 4; ++dc) {
      bf16x8 vb2r = *(const bf16x8*)(posvT + (size_t)(dc * 16 + l16) * 136 + kk * 32 + quad * 8);
      o2[dc] = MFMA16(pa2, vb2r, o2[dc]);
    }
  }

  // per-q scalars live at lane l16=q_loc after butterfly -> shfl from lane q_loc
  float li[4], cl[4], ch[4];
#pragma unroll
  for (int i = 0; i < 4; ++i) {
    const int srcl = quad * 4 + i;
    li[i] = __shfl(linv, srcl);
    cl[i] = __shfl(clow, srcl);
    ch[i] = __shfl(chigh, srcl);
  }

#pragma unroll
  for (int dc = 0; dc < 4; ++dc) {
    const int d = dc * 16 + l16;
    const float pv0 = posv[d], pv1 = posv[128 * 64 + d];
#pragma unroll
    for (int i = 0; i < 4; ++i) {
      const int qg = qw0 + quad * 4 + i;
      if (qg < 1500) {
        const float val = (accf[dc][i] + o2[dc][i] + cl[i] * pv0 + ch[i] * pv1) * li[i];
        hidden[((size_t)(b * 1500 + qg)) * 1024 + (bh & 15) * 64 + d] = f2bf(val);
      }
    }
  }
}

// ---------------- launcher ----------------
extern "C" void kernel_launch(void* const* d_in, const int* in_sizes, int n_in,
                              void* d_out, int out_size, void* d_ws, size_t ws_size,
                              hipStream_t stream) {
  const float* query = (const float*)d_in[0];
  const float* key   = (const float*)d_in[1];
  const float* value = (const float*)d_in[2];
  const float* Wq = (const float*)d_in[3];
  const float* bq = (const float*)d_in[4];
  const float* Wk = (const float*)d_in[5];
  const float* bk = (const float*)d_in[6];
  const float* Wv = (const float*)d_in[7];
  const float* bv = (const float*)d_in[8];
  const float* posk = (const float*)d_in[9];
  const float* posv = (const float*)d_in[10];
  const float* Wfc = (const float*)d_in[11];
  const float* bfc = (const float*)d_in[12];
  float* out = (float*)d_out;

  char* p = (char*)d_ws;
  u16* X = (u16*)p;        p += 3UL * 6016 * 1024 * 2;   // Xq,Xk,Xv (M padded to 6016)
  u16* Wt = (u16*)p;       p += 3UL * 1024 * 1024 * 2;   // Wq_t,Wk_t,Wv_t
  u16* Wfct = (u16*)p;     p += 1024UL * 1024 * 2;
  u16* poskbf = (u16*)p;   p += 144UL * 64 * 2;
  u16* posvT = (u16*)p;    p += 64UL * 136 * 2;
  float* biascat = (float*)p; p += 3UL * 1024 * 4;
  u16* qkv = (u16*)p;      p += 3UL * 4 * 16 * 1536 * 64 * 2;  // q,k,v [B*NH][1536][64]
  u16* hidden = X;                       // X region dead after QKV GEMM
  u16* Vt = X + 6291456;                 // aliases Xk/Xv region, dead after QKV GEMM

  pack_x_kernel<<<dim3(6000, 1, 3), 256, 0, stream>>>(query, key, value, X);
  pack_w_kernel<<<dim3(1025), 256, 0, stream>>>(Wq, Wk, Wv, Wfc, bq, bk, bv, posk, posv,
                                                Wt, Wfct, biascat, poskbf, posvT);

  gemm_bt_kernel<<<dim3(8, 47, 3), 256, 0, stream>>>(
      X, 6016L * 1024, Wt, 1024L * 1024, biascat, 1024L, qkv, nullptr, 0);

  vtrans_kernel<<<dim3(1536), 256, 0, stream>>>(qkv, Vt);

  attn_kernel<<<dim3(1536), 256, 0, stream>>>(qkv, Vt, poskbf, posvT, posv, hidden);

  gemm_bt_kernel<<<dim3(8, 47, 1), 256, 0, stream>>>(
      hidden, 0L, Wfct, 0L, bfc, 0L, nullptr, out, 1);
}